// Round 1
// baseline (1120.414 us; speedup 1.0000x reference)
//
#include <hip/hip_runtime.h>

#define NB 4
#define NS 1024
#define NE 512
#define NH 8
#define ND 64
#define NC 16      // chunks per sequence
#define CSZ 64     // chunk size

static constexpr float FEPS = 1e-6f;

__device__ __forceinline__ float h_log2kap(int h) {
  float kap = (1.0f - exp2f(-5.0f - (float)h)) * 0.8f;
  return log2f(kap);
}
__device__ __forceinline__ float silu_f(float x) {
  return x / (1.0f + __expf(-x));
}

// ---------------- segment id scan (inclusive cumsum of dones) ----------------
__global__ __launch_bounds__(256) void seg_scan_kernel(const int* __restrict__ dones,
                                                       int* __restrict__ seg) {
  __shared__ int s[NS];
  int b = blockIdx.x;
  for (int i = threadIdx.x; i < NS; i += 256) s[i] = (dones[b * NS + i] != 0) ? 1 : 0;
  __syncthreads();
  for (int off = 1; off < NS; off <<= 1) {
    int tv[4];
#pragma unroll
    for (int u = 0; u < 4; u++) {
      int i = threadIdx.x + 256 * u;
      tv[u] = s[i] + ((i >= off) ? s[i - off] : 0);
    }
    __syncthreads();
#pragma unroll
    for (int u = 0; u < 4; u++) s[threadIdx.x + 256 * u] = tv[u];
    __syncthreads();
  }
  for (int i = threadIdx.x; i < NS; i += 256) seg[b * NS + i] = s[i];
}

// ---------------- fp32 GEMM: C[4096,512] = A[4096,512] @ W[512,512] ----------
// MODE 0: C = alpha*acc ; MODE 1: C = silu(acc) * MUL
template <int MODE>
__global__ __launch_bounds__(256) void gemm512_kernel(const float* __restrict__ A,
                                                      const float* __restrict__ W,
                                                      const float* __restrict__ MUL,
                                                      float* __restrict__ C,
                                                      float alpha) {
  __shared__ float As[16][64];  // transposed: As[k][m]
  __shared__ float Bs[16][64];  // Bs[k][n]
  const int t = threadIdx.x;
  const int n0 = blockIdx.x * 64;
  const int m0 = blockIdx.y * 64;
  const int tx = t & 15, ty = t >> 4;
  const int am = t >> 2, akq = (t & 3) * 4;
  const int bk = t >> 4, bnq = (t & 15) * 4;
  const float* Ap = A + (m0 + am) * NE + akq;
  const float* Wp = W + bk * NE + n0 + bnq;
  float acc[4][4] = {};
  for (int kt = 0; kt < NE; kt += 16) {
    float4 av = *(const float4*)(Ap + kt);
    float4 bv = *(const float4*)(Wp + kt * NE);
    As[akq + 0][am] = av.x;
    As[akq + 1][am] = av.y;
    As[akq + 2][am] = av.z;
    As[akq + 3][am] = av.w;
    *(float4*)&Bs[bk][bnq] = bv;
    __syncthreads();
#pragma unroll
    for (int kk = 0; kk < 16; kk++) {
      float a[4], b[4];
      *(float4*)a = *(const float4*)&As[kk][ty * 4];
      *(float4*)b = *(const float4*)&Bs[kk][tx * 4];
#pragma unroll
      for (int ii = 0; ii < 4; ii++)
#pragma unroll
        for (int jj = 0; jj < 4; jj++) acc[ii][jj] += a[ii] * b[jj];
    }
    __syncthreads();
  }
#pragma unroll
  for (int ii = 0; ii < 4; ii++) {
    int row = m0 + ty * 4 + ii;
    int col = n0 + tx * 4;
    float4 r;
    r.x = acc[ii][0] * alpha;
    r.y = acc[ii][1] * alpha;
    r.z = acc[ii][2] * alpha;
    r.w = acc[ii][3] * alpha;
    if (MODE == 1) {
      float4 m = *(const float4*)&MUL[row * NE + col];
      r.x = silu_f(r.x) * m.x;
      r.y = silu_f(r.y) * m.y;
      r.z = silu_f(r.z) * m.z;
      r.w = silu_f(r.w) * m.w;
    }
    *(float4*)&C[row * NE + col] = r;
  }
}

// ---------------- retention pass 1: per-chunk U and carry factor f -----------
__global__ __launch_bounds__(256) void ret_pass1_kernel(
    const float* __restrict__ kmat, const float* __restrict__ vmat,
    const int* __restrict__ seg, const int* __restrict__ ts,
    float* __restrict__ U, float* __restrict__ fbuf) {
  __shared__ float Ks[CSZ * ND];
  __shared__ float Vs[CSZ * ND];
  const int c = blockIdx.x, bh = blockIdx.y;
  const int b = bh >> 3, h = bh & 7;
  const float l2k = h_log2kap(h);
  const int t = threadIdx.x;
  const int e = c * CSZ + CSZ - 1;
  const int seg_e = seg[b * NS + e];
  const float ts_e = (float)ts[b * NS + e];
#pragma unroll
  for (int u0 = 0; u0 < 4; u0++) {
    int u = t + u0 * 256;
    int j = u >> 4;
    int dq = (u & 15) * 4;
    int gpos = b * NS + c * CSZ + j;
    float w = (seg[gpos] == seg_e) ? exp2f((ts_e - (float)ts[gpos]) * l2k) : 0.0f;
    float4 kv = *(const float4*)&kmat[gpos * NE + h * ND + dq];
    kv.x *= w; kv.y *= w; kv.z *= w; kv.w *= w;
    *(float4*)&Ks[j * ND + dq] = kv;
    *(float4*)&Vs[j * ND + dq] = *(const float4*)&vmat[gpos * NE + h * ND + dq];
  }
  __syncthreads();
  const int d = t >> 2;
  const int v4 = (t & 3) * 16;
  float acc[16] = {};
  for (int j = 0; j < CSZ; j++) {
    float kd = Ks[j * ND + d];
#pragma unroll
    for (int u = 0; u < 16; u += 4) {
      float4 vv = *(const float4*)&Vs[j * ND + v4 + u];
      acc[u + 0] += kd * vv.x;
      acc[u + 1] += kd * vv.y;
      acc[u + 2] += kd * vv.z;
      acc[u + 3] += kd * vv.w;
    }
  }
  float* Uo = U + (bh * NC + c) * (ND * ND) + d * ND + v4;
#pragma unroll
  for (int u = 0; u < 16; u += 4)
    *(float4*)&Uo[u] = make_float4(acc[u], acc[u + 1], acc[u + 2], acc[u + 3]);
  if (t == 0) {
    int ps = 0;
    float pt = -1.0f;
    if (c > 0) {
      ps = seg[b * NS + c * CSZ - 1];
      pt = (float)ts[b * NS + c * CSZ - 1];
    }
    fbuf[bh * NC + c] = (seg_e == ps) ? exp2f((ts_e - pt) * l2k) : 0.0f;
  }
}

// ---------------- retention pass 2: scan over chunks, emit P_c and h_new -----
__global__ __launch_bounds__(256) void ret_pass2_kernel(
    const float* __restrict__ U, const float* __restrict__ fbuf,
    const float* __restrict__ hin, float* __restrict__ P,
    float* __restrict__ hout) {
  const int part = blockIdx.x;  // 0..7
  const int bh = blockIdx.y;    // 0..31
  const int idx = part * 512 + threadIdx.x * 2;
  float2 s = *(const float2*)&hin[bh * 4096 + idx];
  for (int c = 0; c < NC; c++) {
    *(float2*)&P[(bh * NC + c) * 4096 + idx] = s;
    float f = fbuf[bh * NC + c];
    float2 u = *(const float2*)&U[(bh * NC + c) * 4096 + idx];
    s.x = u.x + f * s.x;
    s.y = u.y + f * s.y;
  }
  *(float2*)&hout[bh * 4096 + idx] = s;
}

// ---------------- retention pass 3: intra-chunk + cross + groupnorm ----------
__global__ __launch_bounds__(256) void ret_pass3_kernel(
    const float* __restrict__ qmat, const float* __restrict__ kmat,
    const float* __restrict__ vmat, const float* __restrict__ P,
    const int* __restrict__ seg, const int* __restrict__ ts,
    const float* __restrict__ gns, const float* __restrict__ gnb,
    float* __restrict__ y) {
  __shared__ float Qs[CSZ * 68];  // padded stride 68 (bank-spread, 16B aligned)
  __shared__ float KP[CSZ * ND];  // K tile in phase A, then P tile for cross
  __shared__ float Vs[CSZ * ND];
  __shared__ int segs[CSZ];
  __shared__ int tss[CSZ];
  const int c = blockIdx.x, bh = blockIdx.y;
  const int b = bh >> 3, h = bh & 7;
  const float l2k = h_log2kap(h);
  const int t = threadIdx.x;
#pragma unroll
  for (int u0 = 0; u0 < 4; u0++) {
    int u = t + u0 * 256;
    int j = u >> 4;
    int dq = (u & 15) * 4;
    int gofs = (b * NS + c * CSZ + j) * NE + h * ND + dq;
    *(float4*)&Qs[j * 68 + dq] = *(const float4*)&qmat[gofs];
    *(float4*)&KP[j * ND + dq] = *(const float4*)&kmat[gofs];
    *(float4*)&Vs[j * ND + dq] = *(const float4*)&vmat[gofs];
  }
  if (t < CSZ) {
    segs[t] = seg[b * NS + c * CSZ + t];
    tss[t] = ts[b * NS + c * CSZ + t];
  }
  __syncthreads();
  const int i = t >> 2;
  const int jg = (t & 3) * 16;
  const int v4 = jg;
  const int si = segs[i];
  const float tsi = (float)tss[i];
  // phase A: scores for (row i, cols jg..jg+15)
  float sc[16] = {};
  for (int d0 = 0; d0 < ND; d0 += 8) {
    float qr[8];
    *(float4*)&qr[0] = *(const float4*)&Qs[i * 68 + d0];
    *(float4*)&qr[4] = *(const float4*)&Qs[i * 68 + d0 + 4];
#pragma unroll
    for (int jj = 0; jj < 16; jj++) {
      float kr[8];
      *(float4*)&kr[0] = *(const float4*)&KP[(jg + jj) * ND + d0];
      *(float4*)&kr[4] = *(const float4*)&KP[(jg + jj) * ND + d0 + 4];
      float s = sc[jj];
#pragma unroll
      for (int dd = 0; dd < 8; dd++) s += qr[dd] * kr[dd];
      sc[jj] = s;
    }
  }
#pragma unroll
  for (int jj = 0; jj < 16; jj++) {
    int j = jg + jj;
    float w = 0.0f;
    if (j <= i && segs[j] == si) w = exp2f((tsi - (float)tss[j]) * l2k);
    sc[jj] *= w;
  }
  // issue P global loads now (latency hides behind phase B)
  float4 pv[4];
#pragma unroll
  for (int u0 = 0; u0 < 4; u0++)
    pv[u0] = *(const float4*)&P[(bh * NC + c) * 4096 + (t + u0 * 256) * 4];
  // phase B: inner = Sc @ V via quad-shuffle of scores
  float acc[16] = {};
  const int lq = t & 3;
  const int laneBase = (t & 63) & ~3;
#pragma unroll
  for (int r = 0; r < 4; r++) {
    int srcq = (lq + r) & 3;
    int srcLane = laneBase | srcq;
    float scr[16];
#pragma unroll
    for (int jj = 0; jj < 16; jj++) scr[jj] = __shfl(sc[jj], srcLane);
#pragma unroll
    for (int jj = 0; jj < 16; jj++) {
      float s = scr[jj];
      int j = srcq * 16 + jj;
#pragma unroll
      for (int u = 0; u < 16; u += 4) {
        float4 vv = *(const float4*)&Vs[j * ND + v4 + u];
        acc[u + 0] += s * vv.x;
        acc[u + 1] += s * vv.y;
        acc[u + 2] += s * vv.z;
        acc[u + 3] += s * vv.w;
      }
    }
  }
  __syncthreads();  // all phase-A K reads done -> safe to overwrite KP with P
#pragma unroll
  for (int u0 = 0; u0 < 4; u0++)
    *(float4*)&KP[(t + u0 * 256) * 4] = pv[u0];
  __syncthreads();
  // cross term: g_i * q_i @ P_c
  int ps = 0;
  float pt = -1.0f;
  if (c > 0) {
    ps = seg[b * NS + c * CSZ - 1];
    pt = (float)ts[b * NS + c * CSZ - 1];
  }
  float g = (si == ps) ? exp2f((tsi - pt) * l2k) : 0.0f;
  float cr[16] = {};
  for (int d0 = 0; d0 < ND; d0 += 8) {
    float qr[8];
    *(float4*)&qr[0] = *(const float4*)&Qs[i * 68 + d0];
    *(float4*)&qr[4] = *(const float4*)&Qs[i * 68 + d0 + 4];
#pragma unroll
    for (int dd = 0; dd < 8; dd++) {
      float qdv = qr[dd];
#pragma unroll
      for (int u = 0; u < 16; u += 4) {
        float4 pvv = *(const float4*)&KP[(d0 + dd) * ND + v4 + u];
        cr[u + 0] += qdv * pvv.x;
        cr[u + 1] += qdv * pvv.y;
        cr[u + 2] += qdv * pvv.z;
        cr[u + 3] += qdv * pvv.w;
      }
    }
  }
#pragma unroll
  for (int u = 0; u < 16; u++) acc[u] += g * cr[u];
  // groupnorm over the 64-wide row (held by the 4 quad lanes)
  float s1 = 0.f, s2 = 0.f;
#pragma unroll
  for (int u = 0; u < 16; u++) {
    s1 += acc[u];
    s2 += acc[u] * acc[u];
  }
  s1 += __shfl_xor(s1, 1);
  s2 += __shfl_xor(s2, 1);
  s1 += __shfl_xor(s1, 2);
  s2 += __shfl_xor(s2, 2);
  float mu = s1 * (1.0f / 64.0f);
  float var = s2 * (1.0f / 64.0f) - mu * mu;
  float rs = rsqrtf(var + FEPS);
  int yofs = (b * NS + c * CSZ + i) * NE + h * ND + v4;
#pragma unroll
  for (int u = 0; u < 16; u += 4) {
    float4 gs = *(const float4*)&gns[h * ND + v4 + u];
    float4 gb = *(const float4*)&gnb[h * ND + v4 + u];
    float4 o;
    o.x = (acc[u + 0] - mu) * rs * gs.x + gb.x;
    o.y = (acc[u + 1] - mu) * rs * gs.y + gb.y;
    o.z = (acc[u + 2] - mu) * rs * gs.z + gb.z;
    o.w = (acc[u + 3] - mu) * rs * gs.w + gb.w;
    *(float4*)&y[yofs + u] = o;
  }
}

// ---------------- residual RMS norm: out = (a+res)*rsqrt(mean^2)*scale -------
__global__ __launch_bounds__(256) void rms_kernel(const float* __restrict__ a,
                                                  const float* __restrict__ res,
                                                  const float* __restrict__ scale,
                                                  float* __restrict__ out) {
  int row = blockIdx.x * 4 + (threadIdx.x >> 6);
  int lane = threadIdx.x & 63;
  int base = row * NE + lane * 8;
  float x[8], r[8];
  *(float4*)&x[0] = *(const float4*)&a[base];
  *(float4*)&x[4] = *(const float4*)&a[base + 4];
  *(float4*)&r[0] = *(const float4*)&res[base];
  *(float4*)&r[4] = *(const float4*)&res[base + 4];
  float ss = 0.f;
#pragma unroll
  for (int u = 0; u < 8; u++) {
    x[u] += r[u];
    ss += x[u] * x[u];
  }
#pragma unroll
  for (int off = 1; off < 64; off <<= 1) ss += __shfl_xor(ss, off);
  float rsf = rsqrtf(ss * (1.0f / 512.0f) + FEPS);
  float s[8];
  *(float4*)&s[0] = *(const float4*)&scale[lane * 8];
  *(float4*)&s[4] = *(const float4*)&scale[lane * 8 + 4];
  float o[8];
#pragma unroll
  for (int u = 0; u < 8; u++) o[u] = x[u] * rsf * s[u];
  *(float4*)&out[base] = *(float4*)&o[0];
  *(float4*)&out[base + 4] = *(float4*)&o[4];
}

extern "C" void kernel_launch(void* const* d_in, const int* in_sizes, int n_in,
                              void* d_out, int out_size, void* d_ws, size_t ws_size,
                              hipStream_t stream) {
  (void)in_sizes; (void)n_in; (void)out_size; (void)ws_size;
  const float* x = (const float*)d_in[0];
  const float* obs = (const float*)d_in[1];
  const float* hs1 = (const float*)d_in[2];
  const float* hs2 = (const float*)d_in[3];
  const int* dones = (const int*)d_in[4];
  const int* tsid = (const int*)d_in[5];
  const float* ln1 = (const float*)d_in[6];
  const float* ln2 = (const float*)d_in[7];
  const float* ln3 = (const float*)d_in[8];
  const float* r1_wq = (const float*)d_in[9];
  const float* r1_wk = (const float*)d_in[10];
  const float* r1_wv = (const float*)d_in[11];
  const float* r1_wg = (const float*)d_in[12];
  const float* r1_wo = (const float*)d_in[13];
  const float* r1_gs = (const float*)d_in[14];
  const float* r1_gb = (const float*)d_in[15];
  const float* r2_wq = (const float*)d_in[16];
  const float* r2_wk = (const float*)d_in[17];
  const float* r2_wv = (const float*)d_in[18];
  const float* r2_wg = (const float*)d_in[19];
  const float* r2_wo = (const float*)d_in[20];
  const float* r2_gs = (const float*)d_in[21];
  const float* r2_gb = (const float*)d_in[22];
  const float* f_wl = (const float*)d_in[23];
  const float* f_wg = (const float*)d_in[24];
  const float* f_wo = (const float*)d_in[25];

  const size_t NBUF = (size_t)NB * NS * NE;  // 2,097,152 floats
  float* w = (float*)d_ws;
  int* segb = (int*)d_ws;        // 4096 ints
  float* fb = w + 4096;          // 512 floats
  float* B0 = w + 8192;
  float* B1 = B0 + NBUF;
  float* B2 = B1 + NBUF;
  float* B3 = B2 + NBUF;
  float* B4 = B3 + NBUF;
  float* B5 = B4 + NBUF;
  float* B6 = B5 + NBUF;
  float* B7 = B6 + NBUF;

  float* out = (float*)d_out;
  float* hs1o = out + NBUF;
  float* hs2o = hs1o + (size_t)NB * NH * ND * ND;

  dim3 gG(8, 64), gR(16, 32), gP2(8, 32);

  seg_scan_kernel<<<NB, 256, 0, stream>>>(dones, segb);

  // ---- retention layer 1 (k=q=v=x) ----
  gemm512_kernel<0><<<gG, 256, 0, stream>>>(x, r1_wq, nullptr, B0, 1.0f);
  gemm512_kernel<0><<<gG, 256, 0, stream>>>(x, r1_wk, nullptr, B1, 0.125f);
  gemm512_kernel<0><<<gG, 256, 0, stream>>>(x, r1_wv, nullptr, B2, 1.0f);
  ret_pass1_kernel<<<gR, 256, 0, stream>>>(B1, B2, segb, tsid, B3, fb);
  ret_pass2_kernel<<<gP2, 256, 0, stream>>>(B3, fb, hs1, B4, hs1o);
  ret_pass3_kernel<<<gR, 256, 0, stream>>>(B0, B1, B2, B4, segb, tsid, r1_gs, r1_gb, B5);
  gemm512_kernel<1><<<gG, 256, 0, stream>>>(x, r1_wg, B5, B6, 1.0f);   // z1
  gemm512_kernel<0><<<gG, 256, 0, stream>>>(B6, r1_wo, nullptr, B7, 1.0f);  // o1
  rms_kernel<<<1024, 256, 0, stream>>>(B7, x, ln1, B6);                // x2

  // ---- retention layer 2 (k=v=x2, q=obs_rep) ----
  gemm512_kernel<0><<<gG, 256, 0, stream>>>(obs, r2_wq, nullptr, B0, 1.0f);
  gemm512_kernel<0><<<gG, 256, 0, stream>>>(B6, r2_wk, nullptr, B1, 0.125f);
  gemm512_kernel<0><<<gG, 256, 0, stream>>>(B6, r2_wv, nullptr, B2, 1.0f);
  ret_pass1_kernel<<<gR, 256, 0, stream>>>(B1, B2, segb, tsid, B3, fb);
  ret_pass2_kernel<<<gP2, 256, 0, stream>>>(B3, fb, hs2, B4, hs2o);
  ret_pass3_kernel<<<gR, 256, 0, stream>>>(B0, B1, B2, B4, segb, tsid, r2_gs, r2_gb, B5);
  gemm512_kernel<1><<<gG, 256, 0, stream>>>(obs, r2_wg, B5, B0, 1.0f);  // z2
  gemm512_kernel<0><<<gG, 256, 0, stream>>>(B0, r2_wo, nullptr, B1, 1.0f);  // o2
  rms_kernel<<<1024, 256, 0, stream>>>(B1, obs, ln2, B2);               // y

  // ---- FFN ----
  gemm512_kernel<0><<<gG, 256, 0, stream>>>(B2, f_wl, nullptr, B0, 1.0f);   // y@wl
  gemm512_kernel<1><<<gG, 256, 0, stream>>>(B2, f_wg, B0, B1, 1.0f);        // silu(y@wg)*(y@wl)
  gemm512_kernel<0><<<gG, 256, 0, stream>>>(B1, f_wo, nullptr, B3, 1.0f);   // ffn out
  rms_kernel<<<1024, 256, 0, stream>>>(B3, B2, ln3, out);                   // final
}

// Round 2
// 698.988 us; speedup vs baseline: 1.6029x; 1.6029x over previous
//
#include <hip/hip_runtime.h>

#define NB 4
#define NS 1024
#define NE 512
#define NH 8
#define ND 64
#define NC 16      // chunks per sequence
#define CSZ 64     // chunk size

static constexpr float FEPS = 1e-6f;

__device__ __forceinline__ float h_log2kap(int h) {
  float kap = (1.0f - exp2f(-5.0f - (float)h)) * 0.8f;
  return log2f(kap);
}
__device__ __forceinline__ float silu_f(float x) {
  return x / (1.0f + __expf(-x));
}

// ---------------- segment id scan (inclusive cumsum of dones) ----------------
__global__ __launch_bounds__(256) void seg_scan_kernel(const int* __restrict__ dones,
                                                       int* __restrict__ seg) {
  __shared__ int s[NS];
  int b = blockIdx.x;
  for (int i = threadIdx.x; i < NS; i += 256) s[i] = (dones[b * NS + i] != 0) ? 1 : 0;
  __syncthreads();
  for (int off = 1; off < NS; off <<= 1) {
    int tv[4];
#pragma unroll
    for (int u = 0; u < 4; u++) {
      int i = threadIdx.x + 256 * u;
      tv[u] = s[i] + ((i >= off) ? s[i - off] : 0);
    }
    __syncthreads();
#pragma unroll
    for (int u = 0; u < 4; u++) s[threadIdx.x + 256 * u] = tv[u];
    __syncthreads();
  }
  for (int i = threadIdx.x; i < NS; i += 256) seg[b * NS + i] = s[i];
}

// ---------------- fp32 GEMM: C[4096,512] = A[4096,512] @ W[512,512] ----------
// MODE 0: C = alpha*acc ; MODE 1: C = silu(acc) * MUL
template <int MODE>
__global__ __launch_bounds__(256) void gemm512_kernel(const float* __restrict__ A,
                                                      const float* __restrict__ W,
                                                      const float* __restrict__ MUL,
                                                      float* __restrict__ C,
                                                      float alpha) {
  __shared__ float As[16][64];  // transposed: As[k][m]
  __shared__ float Bs[16][64];  // Bs[k][n]
  const int t = threadIdx.x;
  const int n0 = blockIdx.x * 64;
  const int m0 = blockIdx.y * 64;
  const int tx = t & 15, ty = t >> 4;
  const int am = t >> 2, akq = (t & 3) * 4;
  const int bk = t >> 4, bnq = (t & 15) * 4;
  const float* Ap = A + (m0 + am) * NE + akq;
  const float* Wp = W + bk * NE + n0 + bnq;
  float acc[4][4] = {};
  for (int kt = 0; kt < NE; kt += 16) {
    float4 av = *(const float4*)(Ap + kt);
    float4 bv = *(const float4*)(Wp + kt * NE);
    As[akq + 0][am] = av.x;
    As[akq + 1][am] = av.y;
    As[akq + 2][am] = av.z;
    As[akq + 3][am] = av.w;
    *(float4*)&Bs[bk][bnq] = bv;
    __syncthreads();
#pragma unroll
    for (int kk = 0; kk < 16; kk++) {
      float a[4], b[4];
      *(float4*)a = *(const float4*)&As[kk][ty * 4];
      *(float4*)b = *(const float4*)&Bs[kk][tx * 4];
#pragma unroll
      for (int ii = 0; ii < 4; ii++)
#pragma unroll
        for (int jj = 0; jj < 4; jj++) acc[ii][jj] += a[ii] * b[jj];
    }
    __syncthreads();
  }
#pragma unroll
  for (int ii = 0; ii < 4; ii++) {
    int row = m0 + ty * 4 + ii;
    int col = n0 + tx * 4;
    float4 r;
    r.x = acc[ii][0] * alpha;
    r.y = acc[ii][1] * alpha;
    r.z = acc[ii][2] * alpha;
    r.w = acc[ii][3] * alpha;
    if (MODE == 1) {
      float4 m = *(const float4*)&MUL[row * NE + col];
      r.x = silu_f(r.x) * m.x;
      r.y = silu_f(r.y) * m.y;
      r.z = silu_f(r.z) * m.z;
      r.w = silu_f(r.w) * m.w;
    }
    *(float4*)&C[row * NE + col] = r;
  }
}

// ---------------- retention pass 1: per-chunk U and carry factor f -----------
__global__ __launch_bounds__(256) void ret_pass1_kernel(
    const float* __restrict__ kmat, const float* __restrict__ vmat,
    const int* __restrict__ seg, const int* __restrict__ ts,
    float* __restrict__ U, float* __restrict__ fbuf) {
  __shared__ float Ks[CSZ * ND];
  __shared__ float Vs[CSZ * ND];
  const int c = blockIdx.x, bh = blockIdx.y;
  const int b = bh >> 3, h = bh & 7;
  const float l2k = h_log2kap(h);
  const int t = threadIdx.x;
  const int e = c * CSZ + CSZ - 1;
  const int seg_e = seg[b * NS + e];
  const float ts_e = (float)ts[b * NS + e];
#pragma unroll
  for (int u0 = 0; u0 < 4; u0++) {
    int u = t + u0 * 256;
    int j = u >> 4;
    int dq = (u & 15) * 4;
    int gpos = b * NS + c * CSZ + j;
    float w = (seg[gpos] == seg_e) ? exp2f((ts_e - (float)ts[gpos]) * l2k) : 0.0f;
    float4 kv = *(const float4*)&kmat[gpos * NE + h * ND + dq];
    kv.x *= w; kv.y *= w; kv.z *= w; kv.w *= w;
    *(float4*)&Ks[j * ND + dq] = kv;
    *(float4*)&Vs[j * ND + dq] = *(const float4*)&vmat[gpos * NE + h * ND + dq];
  }
  __syncthreads();
  const int d = t >> 2;
  const int v4 = (t & 3) * 16;
  float acc[16] = {};
  for (int j = 0; j < CSZ; j++) {
    float kd = Ks[j * ND + d];
#pragma unroll
    for (int u = 0; u < 16; u += 4) {
      float4 vv = *(const float4*)&Vs[j * ND + v4 + u];
      acc[u + 0] += kd * vv.x;
      acc[u + 1] += kd * vv.y;
      acc[u + 2] += kd * vv.z;
      acc[u + 3] += kd * vv.w;
    }
  }
  float* Uo = U + (bh * NC + c) * (ND * ND) + d * ND + v4;
#pragma unroll
  for (int u = 0; u < 16; u += 4)
    *(float4*)&Uo[u] = make_float4(acc[u], acc[u + 1], acc[u + 2], acc[u + 3]);
  if (t == 0) {
    int ps = 0;
    float pt = -1.0f;
    if (c > 0) {
      ps = seg[b * NS + c * CSZ - 1];
      pt = (float)ts[b * NS + c * CSZ - 1];
    }
    fbuf[bh * NC + c] = (seg_e == ps) ? exp2f((ts_e - pt) * l2k) : 0.0f;
  }
}

// ---------------- retention pass 2: scan over chunks, emit P_c and h_new -----
__global__ __launch_bounds__(256) void ret_pass2_kernel(
    const float* __restrict__ U, const float* __restrict__ fbuf,
    const float* __restrict__ hin, float* __restrict__ P,
    float* __restrict__ hout) {
  const int part = blockIdx.x;  // 0..7
  const int bh = blockIdx.y;    // 0..31
  const int idx = part * 512 + threadIdx.x * 2;
  float2 s = *(const float2*)&hin[bh * 4096 + idx];
  for (int c = 0; c < NC; c++) {
    *(float2*)&P[(bh * NC + c) * 4096 + idx] = s;
    float f = fbuf[bh * NC + c];
    float2 u = *(const float2*)&U[(bh * NC + c) * 4096 + idx];
    s.x = u.x + f * s.x;
    s.y = u.y + f * s.y;
  }
  *(float2*)&hout[bh * 4096 + idx] = s;
}

// ---------------- retention pass 3: intra-chunk + cross + groupnorm ----------
// Spill-free rework: no scr[]/cr[] arrays, scalar shuffles, capped unrolling,
// K rows rotated by 16*(j>>4) floats in LDS to break the 4-way read conflict.
__global__ __launch_bounds__(256, 4) void ret_pass3_kernel(
    const float* __restrict__ qmat, const float* __restrict__ kmat,
    const float* __restrict__ vmat, const float* __restrict__ P,
    const int* __restrict__ seg, const int* __restrict__ ts,
    const float* __restrict__ gns, const float* __restrict__ gnb,
    float* __restrict__ y) {
  __shared__ float Qs[CSZ * 68];  // padded stride 68
  __shared__ float KP[CSZ * ND];  // K tile (rotated) in phase A, then P (flat)
  __shared__ float Vs[CSZ * ND];
  __shared__ int segs[CSZ];
  __shared__ int tss[CSZ];
  const int c = blockIdx.x, bh = blockIdx.y;
  const int b = bh >> 3, h = bh & 7;
  const float l2k = h_log2kap(h);
  const int t = threadIdx.x;
#pragma unroll
  for (int u0 = 0; u0 < 4; u0++) {
    int u = t + u0 * 256;
    int j = u >> 4;
    int dq = (u & 15) * 4;
    int gofs = (b * NS + c * CSZ + j) * NE + h * ND + dq;
    *(float4*)&Qs[j * 68 + dq] = *(const float4*)&qmat[gofs];
    int rot = (dq + (j & 48)) & 63;  // rotate K row by 16*(j>>4)
    *(float4*)&KP[j * 64 + rot] = *(const float4*)&kmat[gofs];
    *(float4*)&Vs[j * 64 + dq] = *(const float4*)&vmat[gofs];
  }
  if (t < CSZ) {
    segs[t] = seg[b * NS + c * CSZ + t];
    tss[t] = ts[b * NS + c * CSZ + t];
  }
  __syncthreads();
  const int i = t >> 2;
  const int lq = t & 3;
  const int jg = lq * 16;
  const int v4 = lq * 16;
  const int si = segs[i];
  const float tsi = (float)tss[i];
  // phase A: raw scores for (row i, cols jg..jg+15)
  float sc[16] = {};
#pragma unroll 1
  for (int d0 = 0; d0 < ND; d0 += 8) {
    float qr[8];
    *(float4*)&qr[0] = *(const float4*)&Qs[i * 68 + d0];
    *(float4*)&qr[4] = *(const float4*)&Qs[i * 68 + d0 + 4];
    const int ra = (d0 + (lq << 4)) & 63;
    const int rb = (d0 + 4 + (lq << 4)) & 63;
#pragma unroll
    for (int jj = 0; jj < 16; jj++) {
      const int jrow = (jg + jj) * 64;
      float kr[8];
      *(float4*)&kr[0] = *(const float4*)&KP[jrow + ra];
      *(float4*)&kr[4] = *(const float4*)&KP[jrow + rb];
      float s = sc[jj];
#pragma unroll
      for (int dd = 0; dd < 8; dd++) s += qr[dd] * kr[dd];
      sc[jj] = s;
    }
  }
  // decay + causal/segment mask
#pragma unroll
  for (int jj = 0; jj < 16; jj++) {
    int j = jg + jj;
    float w = 0.0f;
    if (j <= i && segs[j] == si) w = exp2f((tsi - (float)tss[j]) * l2k);
    sc[jj] *= w;
  }
  // issue P global loads now (latency hides behind phase B)
  float4 pv[4];
#pragma unroll
  for (int u0 = 0; u0 < 4; u0++)
    pv[u0] = *(const float4*)&P[(bh * NC + c) * 4096 + (t + u0 * 256) * 4];
  // phase B: inner = Sc @ V via quad-shuffle of scores (one scalar at a time)
  float acc[16] = {};
  const int laneBase = (t & 63) & ~3;
#pragma unroll 1
  for (int r = 0; r < 4; r++) {
    const int srcq = (lq + r) & 3;
    const int srcLane = laneBase | srcq;
#pragma unroll
    for (int jj = 0; jj < 16; jj++) {
      float s = __shfl(sc[jj], srcLane);
      const int jrow = (srcq * 16 + jj) * 64;
#pragma unroll
      for (int u = 0; u < 16; u += 4) {
        float4 vv = *(const float4*)&Vs[jrow + v4 + u];
        acc[u + 0] += s * vv.x;
        acc[u + 1] += s * vv.y;
        acc[u + 2] += s * vv.z;
        acc[u + 3] += s * vv.w;
      }
    }
  }
  __syncthreads();  // all phase-A K reads done -> safe to overwrite KP with P
#pragma unroll
  for (int u0 = 0; u0 < 4; u0++)
    *(float4*)&KP[(t + u0 * 256) * 4] = pv[u0];
  __syncthreads();
  // cross term: acc += (g * q_i) @ P_c   (g folded into q, no cr[] array)
  int ps = 0;
  float pt = -1.0f;
  if (c > 0) {
    ps = seg[b * NS + c * CSZ - 1];
    pt = (float)ts[b * NS + c * CSZ - 1];
  }
  const float g = (si == ps) ? exp2f((tsi - pt) * l2k) : 0.0f;
#pragma unroll 1
  for (int d0 = 0; d0 < ND; d0 += 8) {
    float qr[8];
    *(float4*)&qr[0] = *(const float4*)&Qs[i * 68 + d0];
    *(float4*)&qr[4] = *(const float4*)&Qs[i * 68 + d0 + 4];
#pragma unroll
    for (int dd = 0; dd < 8; dd++) {
      const float qg = g * qr[dd];
      const int prow = (d0 + dd) * 64;
#pragma unroll
      for (int u = 0; u < 16; u += 4) {
        float4 pvv = *(const float4*)&KP[prow + v4 + u];
        acc[u + 0] += qg * pvv.x;
        acc[u + 1] += qg * pvv.y;
        acc[u + 2] += qg * pvv.z;
        acc[u + 3] += qg * pvv.w;
      }
    }
  }
  // groupnorm over the 64-wide row (held by the 4 quad lanes)
  float s1 = 0.f, s2 = 0.f;
#pragma unroll
  for (int u = 0; u < 16; u++) {
    s1 += acc[u];
    s2 += acc[u] * acc[u];
  }
  s1 += __shfl_xor(s1, 1);
  s2 += __shfl_xor(s2, 1);
  s1 += __shfl_xor(s1, 2);
  s2 += __shfl_xor(s2, 2);
  float mu = s1 * (1.0f / 64.0f);
  float var = s2 * (1.0f / 64.0f) - mu * mu;
  float rs = rsqrtf(var + FEPS);
  int yofs = (b * NS + c * CSZ + i) * NE + h * ND + v4;
#pragma unroll
  for (int u = 0; u < 16; u += 4) {
    float4 gs = *(const float4*)&gns[h * ND + v4 + u];
    float4 gb = *(const float4*)&gnb[h * ND + v4 + u];
    float4 o;
    o.x = (acc[u + 0] - mu) * rs * gs.x + gb.x;
    o.y = (acc[u + 1] - mu) * rs * gs.y + gb.y;
    o.z = (acc[u + 2] - mu) * rs * gs.z + gb.z;
    o.w = (acc[u + 3] - mu) * rs * gs.w + gb.w;
    *(float4*)&y[yofs + u] = o;
  }
}

// ---------------- residual RMS norm: out = (a+res)*rsqrt(mean^2)*scale -------
__global__ __launch_bounds__(256) void rms_kernel(const float* __restrict__ a,
                                                  const float* __restrict__ res,
                                                  const float* __restrict__ scale,
                                                  float* __restrict__ out) {
  int row = blockIdx.x * 4 + (threadIdx.x >> 6);
  int lane = threadIdx.x & 63;
  int base = row * NE + lane * 8;
  float x[8], r[8];
  *(float4*)&x[0] = *(const float4*)&a[base];
  *(float4*)&x[4] = *(const float4*)&a[base + 4];
  *(float4*)&r[0] = *(const float4*)&res[base];
  *(float4*)&r[4] = *(const float4*)&res[base + 4];
  float ss = 0.f;
#pragma unroll
  for (int u = 0; u < 8; u++) {
    x[u] += r[u];
    ss += x[u] * x[u];
  }
#pragma unroll
  for (int off = 1; off < 64; off <<= 1) ss += __shfl_xor(ss, off);
  float rsf = rsqrtf(ss * (1.0f / 512.0f) + FEPS);
  float s[8];
  *(float4*)&s[0] = *(const float4*)&scale[lane * 8];
  *(float4*)&s[4] = *(const float4*)&scale[lane * 8 + 4];
  float o[8];
#pragma unroll
  for (int u = 0; u < 8; u++) o[u] = x[u] * rsf * s[u];
  *(float4*)&out[base] = *(float4*)&o[0];
  *(float4*)&out[base + 4] = *(float4*)&o[4];
}

extern "C" void kernel_launch(void* const* d_in, const int* in_sizes, int n_in,
                              void* d_out, int out_size, void* d_ws, size_t ws_size,
                              hipStream_t stream) {
  (void)in_sizes; (void)n_in; (void)out_size; (void)ws_size;
  const float* x = (const float*)d_in[0];
  const float* obs = (const float*)d_in[1];
  const float* hs1 = (const float*)d_in[2];
  const float* hs2 = (const float*)d_in[3];
  const int* dones = (const int*)d_in[4];
  const int* tsid = (const int*)d_in[5];
  const float* ln1 = (const float*)d_in[6];
  const float* ln2 = (const float*)d_in[7];
  const float* ln3 = (const float*)d_in[8];
  const float* r1_wq = (const float*)d_in[9];
  const float* r1_wk = (const float*)d_in[10];
  const float* r1_wv = (const float*)d_in[11];
  const float* r1_wg = (const float*)d_in[12];
  const float* r1_wo = (const float*)d_in[13];
  const float* r1_gs = (const float*)d_in[14];
  const float* r1_gb = (const float*)d_in[15];
  const float* r2_wq = (const float*)d_in[16];
  const float* r2_wk = (const float*)d_in[17];
  const float* r2_wv = (const float*)d_in[18];
  const float* r2_wg = (const float*)d_in[19];
  const float* r2_wo = (const float*)d_in[20];
  const float* r2_gs = (const float*)d_in[21];
  const float* r2_gb = (const float*)d_in[22];
  const float* f_wl = (const float*)d_in[23];
  const float* f_wg = (const float*)d_in[24];
  const float* f_wo = (const float*)d_in[25];

  const size_t NBUF = (size_t)NB * NS * NE;  // 2,097,152 floats
  float* w = (float*)d_ws;
  int* segb = (int*)d_ws;        // 4096 ints
  float* fb = w + 4096;          // 512 floats
  float* B0 = w + 8192;
  float* B1 = B0 + NBUF;
  float* B2 = B1 + NBUF;
  float* B3 = B2 + NBUF;
  float* B4 = B3 + NBUF;
  float* B5 = B4 + NBUF;
  float* B6 = B5 + NBUF;
  float* B7 = B6 + NBUF;

  float* out = (float*)d_out;
  float* hs1o = out + NBUF;
  float* hs2o = hs1o + (size_t)NB * NH * ND * ND;

  dim3 gG(8, 64), gR(16, 32), gP2(8, 32);

  seg_scan_kernel<<<NB, 256, 0, stream>>>(dones, segb);

  // ---- retention layer 1 (k=q=v=x) ----
  gemm512_kernel<0><<<gG, 256, 0, stream>>>(x, r1_wq, nullptr, B0, 1.0f);
  gemm512_kernel<0><<<gG, 256, 0, stream>>>(x, r1_wk, nullptr, B1, 0.125f);
  gemm512_kernel<0><<<gG, 256, 0, stream>>>(x, r1_wv, nullptr, B2, 1.0f);
  ret_pass1_kernel<<<gR, 256, 0, stream>>>(B1, B2, segb, tsid, B3, fb);
  ret_pass2_kernel<<<gP2, 256, 0, stream>>>(B3, fb, hs1, B4, hs1o);
  ret_pass3_kernel<<<gR, 256, 0, stream>>>(B0, B1, B2, B4, segb, tsid, r1_gs, r1_gb, B5);
  gemm512_kernel<1><<<gG, 256, 0, stream>>>(x, r1_wg, B5, B6, 1.0f);   // z1
  gemm512_kernel<0><<<gG, 256, 0, stream>>>(B6, r1_wo, nullptr, B7, 1.0f);  // o1
  rms_kernel<<<1024, 256, 0, stream>>>(B7, x, ln1, B6);                // x2

  // ---- retention layer 2 (k=v=x2, q=obs_rep) ----
  gemm512_kernel<0><<<gG, 256, 0, stream>>>(obs, r2_wq, nullptr, B0, 1.0f);
  gemm512_kernel<0><<<gG, 256, 0, stream>>>(B6, r2_wk, nullptr, B1, 0.125f);
  gemm512_kernel<0><<<gG, 256, 0, stream>>>(B6, r2_wv, nullptr, B2, 1.0f);
  ret_pass1_kernel<<<gR, 256, 0, stream>>>(B1, B2, segb, tsid, B3, fb);
  ret_pass2_kernel<<<gP2, 256, 0, stream>>>(B3, fb, hs2, B4, hs2o);
  ret_pass3_kernel<<<gR, 256, 0, stream>>>(B0, B1, B2, B4, segb, tsid, r2_gs, r2_gb, B5);
  gemm512_kernel<1><<<gG, 256, 0, stream>>>(obs, r2_wg, B5, B0, 1.0f);  // z2
  gemm512_kernel<0><<<gG, 256, 0, stream>>>(B0, r2_wo, nullptr, B1, 1.0f);  // o2
  rms_kernel<<<1024, 256, 0, stream>>>(B1, obs, ln2, B2);               // y

  // ---- FFN ----
  gemm512_kernel<0><<<gG, 256, 0, stream>>>(B2, f_wl, nullptr, B0, 1.0f);   // y@wl
  gemm512_kernel<1><<<gG, 256, 0, stream>>>(B2, f_wg, B0, B1, 1.0f);        // silu(y@wg)*(y@wl)
  gemm512_kernel<0><<<gG, 256, 0, stream>>>(B1, f_wo, nullptr, B3, 1.0f);   // ffn out
  rms_kernel<<<1024, 256, 0, stream>>>(B3, B2, ln3, out);                   // final
}

// Round 4
// 549.900 us; speedup vs baseline: 2.0375x; 1.2711x over previous
//
#include <hip/hip_runtime.h>

#define NB 4
#define NS 1024
#define NE 512
#define NH 8
#define ND 64
#define NC 16      // chunks per sequence
#define CSZ 64     // chunk size

static constexpr float FEPS = 1e-6f;

typedef __attribute__((ext_vector_type(8))) short short8;
typedef __attribute__((ext_vector_type(4))) float f32x4;

__device__ __forceinline__ float h_log2kap(int h) {
  float kap = (1.0f - exp2f(-5.0f - (float)h)) * 0.8f;
  return log2f(kap);
}
__device__ __forceinline__ float silu_f(float x) {
  return x / (1.0f + __expf(-x));
}
// fp32 -> bf16 round-to-nearest-even, returned in low 16 bits
__device__ __forceinline__ unsigned int f2bf(float f) {
  unsigned int u = __float_as_uint(f);
  return (u + 0x7FFFu + ((u >> 16) & 1u)) >> 16;
}
__device__ __forceinline__ float bf2f(unsigned int h) {
  return __uint_as_float(h << 16);
}
// split f into hi(bf16) + lo(bf16 of residual); returns packed pair
__device__ __forceinline__ void split2(float f, unsigned int& hi, unsigned int& lo) {
  hi = f2bf(f);
  lo = f2bf(f - bf2f(hi));
}

// ---------------- segment id scan (inclusive cumsum of dones) ----------------
__global__ __launch_bounds__(256) void seg_scan_kernel(const int* __restrict__ dones,
                                                       int* __restrict__ seg) {
  __shared__ int s[NS];
  int b = blockIdx.x;
  for (int i = threadIdx.x; i < NS; i += 256) s[i] = (dones[b * NS + i] != 0) ? 1 : 0;
  __syncthreads();
  for (int off = 1; off < NS; off <<= 1) {
    int tv[4];
#pragma unroll
    for (int u = 0; u < 4; u++) {
      int i = threadIdx.x + 256 * u;
      tv[u] = s[i] + ((i >= off) ? s[i - off] : 0);
    }
    __syncthreads();
#pragma unroll
    for (int u = 0; u < 4; u++) s[threadIdx.x + 256 * u] = tv[u];
    __syncthreads();
  }
  for (int i = threadIdx.x; i < NS; i += 256) seg[b * NS + i] = s[i];
}

// ------- split-bf16 MFMA GEMM: O[w] = f(A) @ W[w] * alpha[w], fp32-grade -----
// A [4096,512] fp32; W [512,512] fp32; tile 128(M) x 64(N), BK=32, 4 waves.
// Precision: A=Ah+Al, W=Wh+Wl (bf16 splits); acc += Ah*Wh + Al*Wh + Ah*Wl.
// AMODE 0: A_eff = A.  AMODE 1: A_eff = silu(A) * A2 (elementwise, fused).
struct GArgs {
  const float* A;
  const float* A2;
  const float* W0; const float* W1; const float* W2; const float* W3;
  float* O0; float* O1; float* O2; float* O3;
  float a0, a1, a2, a3;
};

template <int AMODE>
__global__ __launch_bounds__(256) void mfma_gemm_kernel(GArgs g) {
  __shared__ unsigned short Ash[128 * 40];  // [m][k] bf16 hi, row stride 40
  __shared__ unsigned short Asl[128 * 40];  // lo
  __shared__ unsigned short Bsh[64 * 40];   // [n][k] bf16 hi (W transposed)
  __shared__ unsigned short Bsl[64 * 40];   // lo
  const int t = threadIdx.x;
  const int bn = blockIdx.x;
  const int wsel = bn >> 3;
  const int n0 = (bn & 7) * 64;
  const int m0 = blockIdx.y * 128;
  const float* W = wsel == 0 ? g.W0 : wsel == 1 ? g.W1 : wsel == 2 ? g.W2 : g.W3;
  float* O = wsel == 0 ? g.O0 : wsel == 1 ? g.O1 : wsel == 2 ? g.O2 : g.O3;
  const float alpha = wsel == 0 ? g.a0 : wsel == 1 ? g.a1 : wsel == 2 ? g.a2 : g.a3;
  const int lane = t & 63;
  const int wv = t >> 6;            // wave id: m rows [wv*32, wv*32+32)
  const int aq = t & 7;             // A staging: float4 index in 32-wide k row
  const int am = t >> 3;            // A staging: m row base (0..31)
  const int bnn = t & 63;           // B staging: n within tile
  const int bko = (t >> 6) * 8;     // B staging: k octet
  const int frow = lane & 15;       // fragment row
  const int fko = (lane >> 4) * 8;  // fragment k octet

  f32x4 acc[2][4];
#pragma unroll
  for (int i = 0; i < 2; i++)
#pragma unroll
    for (int j = 0; j < 4; j++) acc[i][j] = (f32x4){0.f, 0.f, 0.f, 0.f};

  for (int kt = 0; kt < NE; kt += 32) {
    // ---- stage A tile (128 x 32), split into hi/lo ----
#pragma unroll
    for (int u = 0; u < 4; u++) {
      int mr = am + u * 32;
      size_t gofs = (size_t)(m0 + mr) * NE + kt + aq * 4;
      float4 av = *(const float4*)(g.A + gofs);
      if (AMODE == 1) {
        float4 yv = *(const float4*)(g.A2 + gofs);
        av.x = silu_f(av.x) * yv.x;
        av.y = silu_f(av.y) * yv.y;
        av.z = silu_f(av.z) * yv.z;
        av.w = silu_f(av.w) * yv.w;
      }
      unsigned int hx, lx, hy, ly, hz, lz, hw, lw;
      split2(av.x, hx, lx);
      split2(av.y, hy, ly);
      split2(av.z, hz, lz);
      split2(av.w, hw, lw);
      uint2 ph, pl;
      ph.x = hx | (hy << 16); ph.y = hz | (hw << 16);
      pl.x = lx | (ly << 16); pl.y = lz | (lw << 16);
      *(uint2*)&Ash[mr * 40 + aq * 4] = ph;
      *(uint2*)&Asl[mr * 40 + aq * 4] = pl;
    }
    // ---- stage B tile (32 x 64 -> [n][k]), split into hi/lo ----
    {
      const float* wp = W + (size_t)(kt + bko) * NE + n0 + bnn;
      unsigned int h[8], l[8];
#pragma unroll
      for (int j = 0; j < 8; j++) split2(wp[(size_t)j * NE], h[j], l[j]);
      uint4 ph, pl;
      ph.x = h[0] | (h[1] << 16); ph.y = h[2] | (h[3] << 16);
      ph.z = h[4] | (h[5] << 16); ph.w = h[6] | (h[7] << 16);
      pl.x = l[0] | (l[1] << 16); pl.y = l[2] | (l[3] << 16);
      pl.z = l[4] | (l[5] << 16); pl.w = l[6] | (l[7] << 16);
      *(uint4*)&Bsh[bnn * 40 + bko] = ph;
      *(uint4*)&Bsl[bnn * 40 + bko] = pl;
    }
    __syncthreads();
    // ---- MFMA: 2 m-tiles x 4 n-tiles x 3 precision terms ----
    short8 af0h = *(const short8*)&Ash[(wv * 32 + frow) * 40 + fko];
    short8 af1h = *(const short8*)&Ash[(wv * 32 + 16 + frow) * 40 + fko];
    short8 af0l = *(const short8*)&Asl[(wv * 32 + frow) * 40 + fko];
    short8 af1l = *(const short8*)&Asl[(wv * 32 + 16 + frow) * 40 + fko];
#pragma unroll
    for (int j = 0; j < 4; j++) {
      short8 bfh = *(const short8*)&Bsh[(j * 16 + frow) * 40 + fko];
      short8 bfl = *(const short8*)&Bsl[(j * 16 + frow) * 40 + fko];
      acc[0][j] = __builtin_amdgcn_mfma_f32_16x16x32_bf16(af0h, bfh, acc[0][j], 0, 0, 0);
      acc[0][j] = __builtin_amdgcn_mfma_f32_16x16x32_bf16(af0l, bfh, acc[0][j], 0, 0, 0);
      acc[0][j] = __builtin_amdgcn_mfma_f32_16x16x32_bf16(af0h, bfl, acc[0][j], 0, 0, 0);
      acc[1][j] = __builtin_amdgcn_mfma_f32_16x16x32_bf16(af1h, bfh, acc[1][j], 0, 0, 0);
      acc[1][j] = __builtin_amdgcn_mfma_f32_16x16x32_bf16(af1l, bfh, acc[1][j], 0, 0, 0);
      acc[1][j] = __builtin_amdgcn_mfma_f32_16x16x32_bf16(af1h, bfl, acc[1][j], 0, 0, 0);
    }
    __syncthreads();
  }
  // ---- epilogue: C/D layout col=lane&15, row=(lane>>4)*4+reg ----
#pragma unroll
  for (int i = 0; i < 2; i++) {
    int rb = m0 + wv * 32 + i * 16 + (lane >> 4) * 4;
#pragma unroll
    for (int j = 0; j < 4; j++) {
      int col = n0 + j * 16 + (lane & 15);
#pragma unroll
      for (int r = 0; r < 4; r++)
        O[(size_t)(rb + r) * NE + col] = acc[i][j][r] * alpha;
    }
  }
}

// ---------------- retention pass 1: per-chunk U and carry factor f -----------
__global__ __launch_bounds__(256) void ret_pass1_kernel(
    const float* __restrict__ kmat, const float* __restrict__ vmat,
    const int* __restrict__ seg, const int* __restrict__ ts,
    float* __restrict__ U, float* __restrict__ fbuf) {
  __shared__ float Ks[CSZ * ND];
  __shared__ float Vs[CSZ * ND];
  const int c = blockIdx.x, bh = blockIdx.y;
  const int b = bh >> 3, h = bh & 7;
  const float l2k = h_log2kap(h);
  const int t = threadIdx.x;
  const int e = c * CSZ + CSZ - 1;
  const int seg_e = seg[b * NS + e];
  const float ts_e = (float)ts[b * NS + e];
#pragma unroll
  for (int u0 = 0; u0 < 4; u0++) {
    int u = t + u0 * 256;
    int j = u >> 4;
    int dq = (u & 15) * 4;
    int gpos = b * NS + c * CSZ + j;
    float w = (seg[gpos] == seg_e) ? exp2f((ts_e - (float)ts[gpos]) * l2k) : 0.0f;
    float4 kv = *(const float4*)&kmat[gpos * NE + h * ND + dq];
    kv.x *= w; kv.y *= w; kv.z *= w; kv.w *= w;
    *(float4*)&Ks[j * ND + dq] = kv;
    *(float4*)&Vs[j * ND + dq] = *(const float4*)&vmat[gpos * NE + h * ND + dq];
  }
  __syncthreads();
  const int d = t >> 2;
  const int v4 = (t & 3) * 16;
  float acc[16] = {};
  for (int j = 0; j < CSZ; j++) {
    float kd = Ks[j * ND + d];
#pragma unroll
    for (int u = 0; u < 16; u += 4) {
      float4 vv = *(const float4*)&Vs[j * ND + v4 + u];
      acc[u + 0] += kd * vv.x;
      acc[u + 1] += kd * vv.y;
      acc[u + 2] += kd * vv.z;
      acc[u + 3] += kd * vv.w;
    }
  }
  float* Uo = U + (bh * NC + c) * (ND * ND) + d * ND + v4;
#pragma unroll
  for (int u = 0; u < 16; u += 4)
    *(float4*)&Uo[u] = make_float4(acc[u], acc[u + 1], acc[u + 2], acc[u + 3]);
  if (t == 0) {
    int ps = 0;
    float pt = -1.0f;
    if (c > 0) {
      ps = seg[b * NS + c * CSZ - 1];
      pt = (float)ts[b * NS + c * CSZ - 1];
    }
    fbuf[bh * NC + c] = (seg_e == ps) ? exp2f((ts_e - pt) * l2k) : 0.0f;
  }
}

// ---------------- retention pass 2: scan over chunks, emit P_c and h_new -----
__global__ __launch_bounds__(256) void ret_pass2_kernel(
    const float* __restrict__ U, const float* __restrict__ fbuf,
    const float* __restrict__ hin, float* __restrict__ P,
    float* __restrict__ hout) {
  const int part = blockIdx.x;  // 0..7
  const int bh = blockIdx.y;    // 0..31
  const int idx = part * 512 + threadIdx.x * 2;
  float2 s = *(const float2*)&hin[bh * 4096 + idx];
  for (int c = 0; c < NC; c++) {
    *(float2*)&P[(bh * NC + c) * 4096 + idx] = s;
    float f = fbuf[bh * NC + c];
    float2 u = *(const float2*)&U[(bh * NC + c) * 4096 + idx];
    s.x = u.x + f * s.x;
    s.y = u.y + f * s.y;
  }
  *(float2*)&hout[bh * 4096 + idx] = s;
}

// ---------------- retention pass 3: intra-chunk + cross + groupnorm ----------
__global__ __launch_bounds__(256, 4) void ret_pass3_kernel(
    const float* __restrict__ qmat, const float* __restrict__ kmat,
    const float* __restrict__ vmat, const float* __restrict__ P,
    const int* __restrict__ seg, const int* __restrict__ ts,
    const float* __restrict__ gns, const float* __restrict__ gnb,
    float* __restrict__ y) {
  __shared__ float Qs[CSZ * 68];  // padded stride 68
  __shared__ float KP[CSZ * ND];  // K tile (rotated) in phase A, then P (flat)
  __shared__ float Vs[CSZ * ND];
  __shared__ int segs[CSZ];
  __shared__ int tss[CSZ];
  const int c = blockIdx.x, bh = blockIdx.y;
  const int b = bh >> 3, h = bh & 7;
  const float l2k = h_log2kap(h);
  const int t = threadIdx.x;
#pragma unroll
  for (int u0 = 0; u0 < 4; u0++) {
    int u = t + u0 * 256;
    int j = u >> 4;
    int dq = (u & 15) * 4;
    int gofs = (b * NS + c * CSZ + j) * NE + h * ND + dq;
    *(float4*)&Qs[j * 68 + dq] = *(const float4*)&qmat[gofs];
    int rot = (dq + (j & 48)) & 63;  // rotate K row by 16*(j>>4)
    *(float4*)&KP[j * 64 + rot] = *(const float4*)&kmat[gofs];
    *(float4*)&Vs[j * 64 + dq] = *(const float4*)&vmat[gofs];
  }
  if (t < CSZ) {
    segs[t] = seg[b * NS + c * CSZ + t];
    tss[t] = ts[b * NS + c * CSZ + t];
  }
  __syncthreads();
  const int i = t >> 2;
  const int lq = t & 3;
  const int jg = lq * 16;
  const int v4 = lq * 16;
  const int si = segs[i];
  const float tsi = (float)tss[i];
  float sc[16] = {};
#pragma unroll 1
  for (int d0 = 0; d0 < ND; d0 += 8) {
    float qr[8];
    *(float4*)&qr[0] = *(const float4*)&Qs[i * 68 + d0];
    *(float4*)&qr[4] = *(const float4*)&Qs[i * 68 + d0 + 4];
    const int ra = (d0 + (lq << 4)) & 63;
    const int rb = (d0 + 4 + (lq << 4)) & 63;
#pragma unroll
    for (int jj = 0; jj < 16; jj++) {
      const int jrow = (jg + jj) * 64;
      float kr[8];
      *(float4*)&kr[0] = *(const float4*)&KP[jrow + ra];
      *(float4*)&kr[4] = *(const float4*)&KP[jrow + rb];
      float s = sc[jj];
#pragma unroll
      for (int dd = 0; dd < 8; dd++) s += qr[dd] * kr[dd];
      sc[jj] = s;
    }
  }
#pragma unroll
  for (int jj = 0; jj < 16; jj++) {
    int j = jg + jj;
    float w = 0.0f;
    if (j <= i && segs[j] == si) w = exp2f((tsi - (float)tss[j]) * l2k);
    sc[jj] *= w;
  }
  float4 pv[4];
#pragma unroll
  for (int u0 = 0; u0 < 4; u0++)
    pv[u0] = *(const float4*)&P[(bh * NC + c) * 4096 + (t + u0 * 256) * 4];
  float acc[16] = {};
  const int laneBase = (t & 63) & ~3;
#pragma unroll 1
  for (int r = 0; r < 4; r++) {
    const int srcq = (lq + r) & 3;
    const int srcLane = laneBase | srcq;
#pragma unroll
    for (int jj = 0; jj < 16; jj++) {
      float s = __shfl(sc[jj], srcLane);
      const int jrow = (srcq * 16 + jj) * 64;
#pragma unroll
      for (int u = 0; u < 16; u += 4) {
        float4 vv = *(const float4*)&Vs[jrow + v4 + u];
        acc[u + 0] += s * vv.x;
        acc[u + 1] += s * vv.y;
        acc[u + 2] += s * vv.z;
        acc[u + 3] += s * vv.w;
      }
    }
  }
  __syncthreads();
#pragma unroll
  for (int u0 = 0; u0 < 4; u0++)
    *(float4*)&KP[(t + u0 * 256) * 4] = pv[u0];
  __syncthreads();
  int ps = 0;
  float pt = -1.0f;
  if (c > 0) {
    ps = seg[b * NS + c * CSZ - 1];
    pt = (float)ts[b * NS + c * CSZ - 1];
  }
  const float g = (si == ps) ? exp2f((tsi - pt) * l2k) : 0.0f;
#pragma unroll 1
  for (int d0 = 0; d0 < ND; d0 += 8) {
    float qr[8];
    *(float4*)&qr[0] = *(const float4*)&Qs[i * 68 + d0];
    *(float4*)&qr[4] = *(const float4*)&Qs[i * 68 + d0 + 4];
#pragma unroll
    for (int dd = 0; dd < 8; dd++) {
      const float qg = g * qr[dd];
      const int prow = (d0 + dd) * 64;
#pragma unroll
      for (int u = 0; u < 16; u += 4) {
        float4 pvv = *(const float4*)&KP[prow + v4 + u];
        acc[u + 0] += qg * pvv.x;
        acc[u + 1] += qg * pvv.y;
        acc[u + 2] += qg * pvv.z;
        acc[u + 3] += qg * pvv.w;
      }
    }
  }
  float s1 = 0.f, s2 = 0.f;
#pragma unroll
  for (int u = 0; u < 16; u++) {
    s1 += acc[u];
    s2 += acc[u] * acc[u];
  }
  s1 += __shfl_xor(s1, 1);
  s2 += __shfl_xor(s2, 1);
  s1 += __shfl_xor(s1, 2);
  s2 += __shfl_xor(s2, 2);
  float mu = s1 * (1.0f / 64.0f);
  float var = s2 * (1.0f / 64.0f) - mu * mu;
  float rs = rsqrtf(var + FEPS);
  int yofs = (b * NS + c * CSZ + i) * NE + h * ND + v4;
#pragma unroll
  for (int u = 0; u < 16; u += 4) {
    float4 gs = *(const float4*)&gns[h * ND + v4 + u];
    float4 gb = *(const float4*)&gnb[h * ND + v4 + u];
    float4 o;
    o.x = (acc[u + 0] - mu) * rs * gs.x + gb.x;
    o.y = (acc[u + 1] - mu) * rs * gs.y + gb.y;
    o.z = (acc[u + 2] - mu) * rs * gs.z + gb.z;
    o.w = (acc[u + 3] - mu) * rs * gs.w + gb.w;
    *(float4*)&y[yofs + u] = o;
  }
}

// ---------------- residual RMS norm: out = (a+res)*rsqrt(mean^2)*scale -------
__global__ __launch_bounds__(256) void rms_kernel(const float* __restrict__ a,
                                                  const float* __restrict__ res,
                                                  const float* __restrict__ scale,
                                                  float* __restrict__ out) {
  int row = blockIdx.x * 4 + (threadIdx.x >> 6);
  int lane = threadIdx.x & 63;
  int base = row * NE + lane * 8;
  float x[8], r[8];
  *(float4*)&x[0] = *(const float4*)&a[base];
  *(float4*)&x[4] = *(const float4*)&a[base + 4];
  *(float4*)&r[0] = *(const float4*)&res[base];
  *(float4*)&r[4] = *(const float4*)&res[base + 4];
  float ss = 0.f;
#pragma unroll
  for (int u = 0; u < 8; u++) {
    x[u] += r[u];
    ss += x[u] * x[u];
  }
#pragma unroll
  for (int off = 1; off < 64; off <<= 1) ss += __shfl_xor(ss, off);
  float rsf = rsqrtf(ss * (1.0f / 512.0f) + FEPS);
  float s[8];
  *(float4*)&s[0] = *(const float4*)&scale[lane * 8];
  *(float4*)&s[4] = *(const float4*)&scale[lane * 8 + 4];
  float o[8];
#pragma unroll
  for (int u = 0; u < 8; u++) o[u] = x[u] * rsf * s[u];
  *(float4*)&out[base] = *(float4*)&o[0];
  *(float4*)&out[base + 4] = *(float4*)&o[4];
}

extern "C" void kernel_launch(void* const* d_in, const int* in_sizes, int n_in,
                              void* d_out, int out_size, void* d_ws, size_t ws_size,
                              hipStream_t stream) {
  (void)in_sizes; (void)n_in; (void)out_size; (void)ws_size;
  const float* x = (const float*)d_in[0];
  const float* obs = (const float*)d_in[1];
  const float* hs1 = (const float*)d_in[2];
  const float* hs2 = (const float*)d_in[3];
  const int* dones = (const int*)d_in[4];
  const int* tsid = (const int*)d_in[5];
  const float* ln1 = (const float*)d_in[6];
  const float* ln2 = (const float*)d_in[7];
  const float* ln3 = (const float*)d_in[8];
  const float* r1_wq = (const float*)d_in[9];
  const float* r1_wk = (const float*)d_in[10];
  const float* r1_wv = (const float*)d_in[11];
  const float* r1_wg = (const float*)d_in[12];
  const float* r1_wo = (const float*)d_in[13];
  const float* r1_gs = (const float*)d_in[14];
  const float* r1_gb = (const float*)d_in[15];
  const float* r2_wq = (const float*)d_in[16];
  const float* r2_wk = (const float*)d_in[17];
  const float* r2_wv = (const float*)d_in[18];
  const float* r2_wg = (const float*)d_in[19];
  const float* r2_wo = (const float*)d_in[20];
  const float* r2_gs = (const float*)d_in[21];
  const float* r2_gb = (const float*)d_in[22];
  const float* f_wl = (const float*)d_in[23];
  const float* f_wg = (const float*)d_in[24];
  const float* f_wo = (const float*)d_in[25];

  const size_t NBUF = (size_t)NB * NS * NE;  // 2,097,152 floats
  float* w = (float*)d_ws;
  int* segb = (int*)d_ws;        // 4096 ints
  float* fb = w + 4096;          // 512 floats
  float* B0 = w + 8192;
  float* B1 = B0 + NBUF;
  float* B2 = B1 + NBUF;
  float* B3 = B2 + NBUF;
  float* B4 = B3 + NBUF;
  float* B5 = B4 + NBUF;
  float* B6 = B5 + NBUF;
  float* B7 = B6 + NBUF;

  float* out = (float*)d_out;
  float* hs1o = out + NBUF;
  float* hs2o = hs1o + (size_t)NB * NH * ND * ND;

  dim3 gR(16, 32), gP2(8, 32);

  seg_scan_kernel<<<NB, 256, 0, stream>>>(dones, segb);

  // ---- retention layer 1 (q=k=v=g from x): one NW=4 GEMM ----
  {
    GArgs a = {x, nullptr, r1_wq, r1_wk, r1_wv, r1_wg, B0, B1, B2, B3,
               1.0f, 0.125f, 1.0f, 1.0f};
    mfma_gemm_kernel<0><<<dim3(32, 32), 256, 0, stream>>>(a);
  }
  ret_pass1_kernel<<<gR, 256, 0, stream>>>(B1, B2, segb, tsid, B4, fb);
  ret_pass2_kernel<<<gP2, 256, 0, stream>>>(B4, fb, hs1, B5, hs1o);
  ret_pass3_kernel<<<gR, 256, 0, stream>>>(B0, B1, B2, B5, segb, tsid, r1_gs, r1_gb, B6);
  {  // o1 = (silu(g1) * y1) @ wo
    GArgs a = {B3, B6, r1_wo, nullptr, nullptr, nullptr, B7, nullptr, nullptr, nullptr,
               1.0f, 1.0f, 1.0f, 1.0f};
    mfma_gemm_kernel<1><<<dim3(8, 32), 256, 0, stream>>>(a);
  }
  rms_kernel<<<1024, 256, 0, stream>>>(B7, x, ln1, B1);  // x2 -> B1

  // ---- retention layer 2 (q,g from obs; k,v from x2) ----
  {
    GArgs a = {obs, nullptr, r2_wq, r2_wg, nullptr, nullptr, B0, B2, nullptr, nullptr,
               1.0f, 1.0f, 1.0f, 1.0f};
    mfma_gemm_kernel<0><<<dim3(16, 32), 256, 0, stream>>>(a);
  }
  {
    GArgs a = {B1, nullptr, r2_wk, r2_wv, nullptr, nullptr, B3, B4, nullptr, nullptr,
               0.125f, 1.0f, 1.0f, 1.0f};
    mfma_gemm_kernel<0><<<dim3(16, 32), 256, 0, stream>>>(a);
  }
  ret_pass1_kernel<<<gR, 256, 0, stream>>>(B3, B4, segb, tsid, B5, fb);
  ret_pass2_kernel<<<gP2, 256, 0, stream>>>(B5, fb, hs2, B6, hs2o);
  ret_pass3_kernel<<<gR, 256, 0, stream>>>(B0, B3, B4, B6, segb, tsid, r2_gs, r2_gb, B7);
  {  // o2 = (silu(g2) * y2) @ wo
    GArgs a = {B2, B7, r2_wo, nullptr, nullptr, nullptr, B0, nullptr, nullptr, nullptr,
               1.0f, 1.0f, 1.0f, 1.0f};
    mfma_gemm_kernel<1><<<dim3(8, 32), 256, 0, stream>>>(a);
  }
  rms_kernel<<<1024, 256, 0, stream>>>(B0, obs, ln2, B2);  // y -> B2

  // ---- FFN ----
  {
    GArgs a = {B2, nullptr, f_wg, f_wl, nullptr, nullptr, B3, B4, nullptr, nullptr,
               1.0f, 1.0f, 1.0f, 1.0f};
    mfma_gemm_kernel<0><<<dim3(16, 32), 256, 0, stream>>>(a);
  }
  {  // ffn = (silu(y@wg) * (y@wl)) @ wo
    GArgs a = {B3, B4, f_wo, nullptr, nullptr, nullptr, B5, nullptr, nullptr, nullptr,
               1.0f, 1.0f, 1.0f, 1.0f};
    mfma_gemm_kernel<1><<<dim3(8, 32), 256, 0, stream>>>(a);
  }
  rms_kernel<<<1024, 256, 0, stream>>>(B5, B2, ln3, out);  // final
}

// Round 5
// 319.155 us; speedup vs baseline: 3.5106x; 1.7230x over previous
//
#include <hip/hip_runtime.h>

#define NB 4
#define NS 1024
#define NE 512
#define NH 8
#define ND 64
#define NC 16      // chunks per sequence
#define CSZ 64     // chunk size

static constexpr float FEPS = 1e-6f;

typedef _Float16 half_t;
typedef __attribute__((ext_vector_type(8))) _Float16 f16x8;
typedef __attribute__((ext_vector_type(4))) _Float16 f16x4;
typedef __attribute__((ext_vector_type(4))) float f32x4;

__device__ __forceinline__ float h_log2kap(int h) {
  float kap = (1.0f - exp2f(-5.0f - (float)h)) * 0.8f;
  return log2f(kap);
}
__device__ __forceinline__ float silu_f(float x) {
  return x / (1.0f + __expf(-x));
}

// ---------------- segment id scan (inclusive cumsum of dones) ----------------
__global__ __launch_bounds__(256) void seg_scan_kernel(const int* __restrict__ dones,
                                                       int* __restrict__ seg) {
  __shared__ int s[NS];
  int b = blockIdx.x;
  for (int i = threadIdx.x; i < NS; i += 256) s[i] = (dones[b * NS + i] != 0) ? 1 : 0;
  __syncthreads();
  for (int off = 1; off < NS; off <<= 1) {
    int tv[4];
#pragma unroll
    for (int u = 0; u < 4; u++) {
      int i = threadIdx.x + 256 * u;
      tv[u] = s[i] + ((i >= off) ? s[i - off] : 0);
    }
    __syncthreads();
#pragma unroll
    for (int u = 0; u < 4; u++) s[threadIdx.x + 256 * u] = tv[u];
    __syncthreads();
  }
  for (int i = threadIdx.x; i < NS; i += 256) seg[b * NS + i] = s[i];
}

// -------- weight convert+transpose: W[k][n] fp32 -> Wt[n][k] fp16, 13 mats ---
struct WCArgs {
  const float* src[13];
  half_t* dst;
};
__global__ __launch_bounds__(256) void wconv_kernel(WCArgs a) {
  __shared__ half_t T[64][72];  // [k][n] tile, padded
  const int t = threadIdx.x;
  const int w = blockIdx.y;
  const int kt = (blockIdx.x & 7) * 64;
  const int nt = (blockIdx.x >> 3) * 64;
  const float* src = a.src[w] + (size_t)kt * NE + nt;
  const int c = t & 63;
  for (int r = t >> 6; r < 64; r += 4) T[r][c] = (half_t)src[(size_t)r * NE + c];
  __syncthreads();
  const int n = t >> 2, kq = (t & 3) * 16;
  half_t* dst = a.dst + (size_t)w * NE * NE + (size_t)(nt + n) * NE + kt + kq;
  f16x8 o0, o1;
#pragma unroll
  for (int j = 0; j < 8; j++) {
    o0[j] = T[kq + j][n];
    o1[j] = T[kq + 8 + j][n];
  }
  *(f16x8*)dst = o0;
  *(f16x8*)(dst + 8) = o1;
}

// ---------------- elementwise fp32 -> fp16 -----------------------------------
__global__ __launch_bounds__(256) void conv_f2h_kernel(const float* __restrict__ src,
                                                       half_t* __restrict__ dst) {
  int i = (blockIdx.x * 256 + threadIdx.x) * 8;
  float4 v0 = *(const float4*)&src[i];
  float4 v1 = *(const float4*)&src[i + 4];
  f16x8 h;
  h[0] = (half_t)v0.x; h[1] = (half_t)v0.y; h[2] = (half_t)v0.z; h[3] = (half_t)v0.w;
  h[4] = (half_t)v1.x; h[5] = (half_t)v1.y; h[6] = (half_t)v1.z; h[7] = (half_t)v1.w;
  *(f16x8*)&dst[i] = h;
}

// ---------------- elementwise silu(g)*l -> fp16 ------------------------------
__global__ __launch_bounds__(256) void silu_mul_conv_kernel(const float* __restrict__ g,
                                                            const float* __restrict__ l,
                                                            half_t* __restrict__ dst) {
  int i = (blockIdx.x * 256 + threadIdx.x) * 8;
  float4 g0 = *(const float4*)&g[i];
  float4 g1 = *(const float4*)&g[i + 4];
  float4 l0 = *(const float4*)&l[i];
  float4 l1 = *(const float4*)&l[i + 4];
  f16x8 h;
  h[0] = (half_t)(silu_f(g0.x) * l0.x); h[1] = (half_t)(silu_f(g0.y) * l0.y);
  h[2] = (half_t)(silu_f(g0.z) * l0.z); h[3] = (half_t)(silu_f(g0.w) * l0.w);
  h[4] = (half_t)(silu_f(g1.x) * l1.x); h[5] = (half_t)(silu_f(g1.y) * l1.y);
  h[6] = (half_t)(silu_f(g1.z) * l1.z); h[7] = (half_t)(silu_f(g1.w) * l1.w);
  *(f16x8*)&dst[i] = h;
}

// ---------------- fp16 MFMA GEMM: O[w] = A[w] @ Wt[w]^T * alpha[w] -----------
// A[w]: [4096][512] fp16; Wt[w]: [n][k] fp16 (pre-transposed). Tile 128x64,
// BK=32, 4 waves. LDS swizzle: octet (r,o) at physical p=(o+(r>>1))&3 -> b128
// reads are exactly 2-way bank-aliased (free, m136).
struct GArgs {
  const half_t *A0, *A1, *A2, *A3;
  const half_t *W0, *W1, *W2, *W3;
  float *O0, *O1, *O2, *O3;
  float a0, a1, a2, a3;
};

__global__ __launch_bounds__(256, 6) void mfma_gemm_kernel(GArgs g) {
  __shared__ half_t As[128 * 32];
  __shared__ half_t Bs[64 * 32];
  const int t = threadIdx.x;
  const int bn = blockIdx.x;
  const int wsel = bn >> 3;
  const int n0 = (bn & 7) * 64;
  const int m0 = blockIdx.y * 128;
  const half_t* A = wsel == 0 ? g.A0 : wsel == 1 ? g.A1 : wsel == 2 ? g.A2 : g.A3;
  const half_t* W = wsel == 0 ? g.W0 : wsel == 1 ? g.W1 : wsel == 2 ? g.W2 : g.W3;
  float* O = wsel == 0 ? g.O0 : wsel == 1 ? g.O1 : wsel == 2 ? g.O2 : g.O3;
  const float alpha = wsel == 0 ? g.a0 : wsel == 1 ? g.a1 : wsel == 2 ? g.a2 : g.a3;
  const int lane = t & 63;
  const int wv = t >> 6;
  const int ar = t >> 1;         // A staging: row 0..127
  const int ae = t & 1;          // A staging: 16-half chunk
  const int brn = t >> 2;        // B staging: n-row 0..63
  const int bo = t & 3;          // B staging: k-octet
  const int frow = lane & 15;
  const int fo = lane >> 4;      // fragment k-octet

  f32x4 acc[2][4];
#pragma unroll
  for (int i = 0; i < 2; i++)
#pragma unroll
    for (int j = 0; j < 4; j++) acc[i][j] = (f32x4){0.f, 0.f, 0.f, 0.f};

  // precomputed fragment LDS offsets (swizzled)
  const int ra0 = wv * 32 + frow;
  const int ra1 = ra0 + 16;
  const int offA0 = ra0 * 32 + (((fo + (ra0 >> 1)) & 3) * 8);
  const int offA1 = ra1 * 32 + (((fo + (ra1 >> 1)) & 3) * 8);
  int offB[4];
#pragma unroll
  for (int j = 0; j < 4; j++) {
    int rb = j * 16 + frow;
    offB[j] = rb * 32 + (((fo + (rb >> 1)) & 3) * 8);
  }
  const int p0 = ((2 * ae + 0) + (ar >> 1)) & 3;
  const int p1 = ((2 * ae + 1) + (ar >> 1)) & 3;
  const int pb = (bo + (brn >> 1)) & 3;

  for (int kt = 0; kt < NE; kt += 32) {
    const half_t* ap = A + (size_t)(m0 + ar) * NE + kt + ae * 16;
    uint4 av0 = *(const uint4*)ap;
    uint4 av1 = *(const uint4*)(ap + 8);
    const half_t* wp = W + (size_t)(n0 + brn) * NE + kt + bo * 8;
    uint4 bv = *(const uint4*)wp;
    *(uint4*)&As[ar * 32 + p0 * 8] = av0;
    *(uint4*)&As[ar * 32 + p1 * 8] = av1;
    *(uint4*)&Bs[brn * 32 + pb * 8] = bv;
    __syncthreads();
    f16x8 af0 = *(const f16x8*)&As[offA0];
    f16x8 af1 = *(const f16x8*)&As[offA1];
#pragma unroll
    for (int j = 0; j < 4; j++) {
      f16x8 bf = *(const f16x8*)&Bs[offB[j]];
      acc[0][j] = __builtin_amdgcn_mfma_f32_16x16x32_f16(af0, bf, acc[0][j], 0, 0, 0);
      acc[1][j] = __builtin_amdgcn_mfma_f32_16x16x32_f16(af1, bf, acc[1][j], 0, 0, 0);
    }
    __syncthreads();
  }
  // epilogue: C/D layout col=lane&15, row=(lane>>4)*4+reg
#pragma unroll
  for (int i = 0; i < 2; i++) {
    int rb = m0 + wv * 32 + i * 16 + (lane >> 4) * 4;
#pragma unroll
    for (int j = 0; j < 4; j++) {
      int col = n0 + j * 16 + (lane & 15);
#pragma unroll
      for (int r = 0; r < 4; r++)
        O[(size_t)(rb + r) * NE + col] = acc[i][j][r] * alpha;
    }
  }
}

// ---------------- retention pass 1: per-chunk U and carry factor f -----------
__global__ __launch_bounds__(256) void ret_pass1_kernel(
    const float* __restrict__ kmat, const float* __restrict__ vmat,
    const int* __restrict__ seg, const int* __restrict__ ts,
    float* __restrict__ U, float* __restrict__ fbuf) {
  __shared__ float Ks[CSZ * ND];
  __shared__ float Vs[CSZ * ND];
  const int c = blockIdx.x, bh = blockIdx.y;
  const int b = bh >> 3, h = bh & 7;
  const float l2k = h_log2kap(h);
  const int t = threadIdx.x;
  const int e = c * CSZ + CSZ - 1;
  const int seg_e = seg[b * NS + e];
  const float ts_e = (float)ts[b * NS + e];
#pragma unroll
  for (int u0 = 0; u0 < 4; u0++) {
    int u = t + u0 * 256;
    int j = u >> 4;
    int dq = (u & 15) * 4;
    int gpos = b * NS + c * CSZ + j;
    float w = (seg[gpos] == seg_e) ? exp2f((ts_e - (float)ts[gpos]) * l2k) : 0.0f;
    float4 kv = *(const float4*)&kmat[gpos * NE + h * ND + dq];
    kv.x *= w; kv.y *= w; kv.z *= w; kv.w *= w;
    *(float4*)&Ks[j * ND + dq] = kv;
    *(float4*)&Vs[j * ND + dq] = *(const float4*)&vmat[gpos * NE + h * ND + dq];
  }
  __syncthreads();
  const int d = t >> 2;
  const int v4 = (t & 3) * 16;
  float acc[16] = {};
  for (int j = 0; j < CSZ; j++) {
    float kd = Ks[j * ND + d];
#pragma unroll
    for (int u = 0; u < 16; u += 4) {
      float4 vv = *(const float4*)&Vs[j * ND + v4 + u];
      acc[u + 0] += kd * vv.x;
      acc[u + 1] += kd * vv.y;
      acc[u + 2] += kd * vv.z;
      acc[u + 3] += kd * vv.w;
    }
  }
  float* Uo = U + (bh * NC + c) * (ND * ND) + d * ND + v4;
#pragma unroll
  for (int u = 0; u < 16; u += 4)
    *(float4*)&Uo[u] = make_float4(acc[u], acc[u + 1], acc[u + 2], acc[u + 3]);
  if (t == 0) {
    int ps = 0;
    float pt = -1.0f;
    if (c > 0) {
      ps = seg[b * NS + c * CSZ - 1];
      pt = (float)ts[b * NS + c * CSZ - 1];
    }
    fbuf[bh * NC + c] = (seg_e == ps) ? exp2f((ts_e - pt) * l2k) : 0.0f;
  }
}

// -------- retention pass 2: scan over chunks (U/P may alias: read-first) -----
__global__ __launch_bounds__(256) void ret_pass2_kernel(
    const float* __restrict__ U, const float* __restrict__ fbuf,
    const float* __restrict__ hin, float* __restrict__ P,
    float* __restrict__ hout) {
  const int part = blockIdx.x;  // 0..7
  const int bh = blockIdx.y;    // 0..31
  const int idx = part * 512 + threadIdx.x * 2;
  float2 s = *(const float2*)&hin[bh * 4096 + idx];
  for (int c = 0; c < NC; c++) {
    float f = fbuf[bh * NC + c];
    float2 u = *(const float2*)&U[(bh * NC + c) * 4096 + idx];  // read BEFORE write
    *(float2*)&P[(bh * NC + c) * 4096 + idx] = s;
    s.x = u.x + f * s.x;
    s.y = u.y + f * s.y;
  }
  *(float2*)&hout[bh * 4096 + idx] = s;
}

// -------- retention pass 3: intra-chunk + cross + groupnorm + silu-gate ------
// Output: fp16 A-matrix for the @wo GEMM: y16 = fp16(silu(g) * groupnorm(ret))
__global__ __launch_bounds__(256, 4) void ret_pass3_kernel(
    const float* __restrict__ qmat, const float* __restrict__ kmat,
    const float* __restrict__ vmat, const float* __restrict__ P,
    const float* __restrict__ gmat,
    const int* __restrict__ seg, const int* __restrict__ ts,
    const float* __restrict__ gns, const float* __restrict__ gnb,
    half_t* __restrict__ y16) {
  __shared__ float Qs[CSZ * 68];  // padded stride 68
  __shared__ float KP[CSZ * ND];  // K tile (rotated) in phase A, then P (flat)
  __shared__ float Vs[CSZ * ND];
  __shared__ int segs[CSZ];
  __shared__ int tss[CSZ];
  const int c = blockIdx.x, bh = blockIdx.y;
  const int b = bh >> 3, h = bh & 7;
  const float l2k = h_log2kap(h);
  const int t = threadIdx.x;
#pragma unroll
  for (int u0 = 0; u0 < 4; u0++) {
    int u = t + u0 * 256;
    int j = u >> 4;
    int dq = (u & 15) * 4;
    int gofs = (b * NS + c * CSZ + j) * NE + h * ND + dq;
    *(float4*)&Qs[j * 68 + dq] = *(const float4*)&qmat[gofs];
    int rot = (dq + (j & 48)) & 63;  // rotate K row by 16*(j>>4)
    *(float4*)&KP[j * 64 + rot] = *(const float4*)&kmat[gofs];
    *(float4*)&Vs[j * 64 + dq] = *(const float4*)&vmat[gofs];
  }
  if (t < CSZ) {
    segs[t] = seg[b * NS + c * CSZ + t];
    tss[t] = ts[b * NS + c * CSZ + t];
  }
  __syncthreads();
  const int i = t >> 2;
  const int lq = t & 3;
  const int jg = lq * 16;
  const int v4 = lq * 16;
  const int si = segs[i];
  const float tsi = (float)tss[i];
  float sc[16] = {};
#pragma unroll 1
  for (int d0 = 0; d0 < ND; d0 += 8) {
    float qr[8];
    *(float4*)&qr[0] = *(const float4*)&Qs[i * 68 + d0];
    *(float4*)&qr[4] = *(const float4*)&Qs[i * 68 + d0 + 4];
    const int ra = (d0 + (lq << 4)) & 63;
    const int rb = (d0 + 4 + (lq << 4)) & 63;
#pragma unroll
    for (int jj = 0; jj < 16; jj++) {
      const int jrow = (jg + jj) * 64;
      float kr[8];
      *(float4*)&kr[0] = *(const float4*)&KP[jrow + ra];
      *(float4*)&kr[4] = *(const float4*)&KP[jrow + rb];
      float s = sc[jj];
#pragma unroll
      for (int dd = 0; dd < 8; dd++) s += qr[dd] * kr[dd];
      sc[jj] = s;
    }
  }
#pragma unroll
  for (int jj = 0; jj < 16; jj++) {
    int j = jg + jj;
    float w = 0.0f;
    if (j <= i && segs[j] == si) w = exp2f((tsi - (float)tss[j]) * l2k);
    sc[jj] *= w;
  }
  float4 pv[4];
#pragma unroll
  for (int u0 = 0; u0 < 4; u0++)
    pv[u0] = *(const float4*)&P[(bh * NC + c) * 4096 + (t + u0 * 256) * 4];
  float acc[16] = {};
  const int laneBase = (t & 63) & ~3;
#pragma unroll 1
  for (int r = 0; r < 4; r++) {
    const int srcq = (lq + r) & 3;
    const int srcLane = laneBase | srcq;
#pragma unroll
    for (int jj = 0; jj < 16; jj++) {
      float s = __shfl(sc[jj], srcLane);
      const int jrow = (srcq * 16 + jj) * 64;
#pragma unroll
      for (int u = 0; u < 16; u += 4) {
        float4 vv = *(const float4*)&Vs[jrow + v4 + u];
        acc[u + 0] += s * vv.x;
        acc[u + 1] += s * vv.y;
        acc[u + 2] += s * vv.z;
        acc[u + 3] += s * vv.w;
      }
    }
  }
  __syncthreads();
#pragma unroll
  for (int u0 = 0; u0 < 4; u0++)
    *(float4*)&KP[(t + u0 * 256) * 4] = pv[u0];
  __syncthreads();
  int ps = 0;
  float pt = -1.0f;
  if (c > 0) {
    ps = seg[b * NS + c * CSZ - 1];
    pt = (float)ts[b * NS + c * CSZ - 1];
  }
  const float g = (si == ps) ? exp2f((tsi - pt) * l2k) : 0.0f;
#pragma unroll 1
  for (int d0 = 0; d0 < ND; d0 += 8) {
    float qr[8];
    *(float4*)&qr[0] = *(const float4*)&Qs[i * 68 + d0];
    *(float4*)&qr[4] = *(const float4*)&Qs[i * 68 + d0 + 4];
#pragma unroll
    for (int dd = 0; dd < 8; dd++) {
      const float qg = g * qr[dd];
      const int prow = (d0 + dd) * 64;
#pragma unroll
      for (int u = 0; u < 16; u += 4) {
        float4 pvv = *(const float4*)&KP[prow + v4 + u];
        acc[u + 0] += qg * pvv.x;
        acc[u + 1] += qg * pvv.y;
        acc[u + 2] += qg * pvv.z;
        acc[u + 3] += qg * pvv.w;
      }
    }
  }
  float s1 = 0.f, s2 = 0.f;
#pragma unroll
  for (int u = 0; u < 16; u++) {
    s1 += acc[u];
    s2 += acc[u] * acc[u];
  }
  s1 += __shfl_xor(s1, 1);
  s2 += __shfl_xor(s2, 1);
  s1 += __shfl_xor(s1, 2);
  s2 += __shfl_xor(s2, 2);
  float mu = s1 * (1.0f / 64.0f);
  float var = s2 * (1.0f / 64.0f) - mu * mu;
  float rs = rsqrtf(var + FEPS);
  int yofs = (b * NS + c * CSZ + i) * NE + h * ND + v4;
#pragma unroll
  for (int u = 0; u < 16; u += 4) {
    float4 gs = *(const float4*)&gns[h * ND + v4 + u];
    float4 gb = *(const float4*)&gnb[h * ND + v4 + u];
    float4 gg = *(const float4*)&gmat[yofs + u];
    f16x4 hv;
    hv[0] = (half_t)(silu_f(gg.x) * ((acc[u + 0] - mu) * rs * gs.x + gb.x));
    hv[1] = (half_t)(silu_f(gg.y) * ((acc[u + 1] - mu) * rs * gs.y + gb.y));
    hv[2] = (half_t)(silu_f(gg.z) * ((acc[u + 2] - mu) * rs * gs.z + gb.z));
    hv[3] = (half_t)(silu_f(gg.w) * ((acc[u + 3] - mu) * rs * gs.w + gb.w));
    *(f16x4*)&y16[yofs + u] = hv;
  }
}

// ------- residual RMS norm; OMODE 0: fp32 out, 1: fp16 out, 2: both ----------
template <int OMODE>
__global__ __launch_bounds__(256) void rms_kernel(const float* __restrict__ a,
                                                  const float* __restrict__ res,
                                                  const float* __restrict__ scale,
                                                  float* __restrict__ outf,
                                                  half_t* __restrict__ outh) {
  int row = blockIdx.x * 4 + (threadIdx.x >> 6);
  int lane = threadIdx.x & 63;
  int base = row * NE + lane * 8;
  float x[8], r[8];
  *(float4*)&x[0] = *(const float4*)&a[base];
  *(float4*)&x[4] = *(const float4*)&a[base + 4];
  *(float4*)&r[0] = *(const float4*)&res[base];
  *(float4*)&r[4] = *(const float4*)&res[base + 4];
  float ss = 0.f;
#pragma unroll
  for (int u = 0; u < 8; u++) {
    x[u] += r[u];
    ss += x[u] * x[u];
  }
#pragma unroll
  for (int off = 1; off < 64; off <<= 1) ss += __shfl_xor(ss, off);
  float rsf = rsqrtf(ss * (1.0f / 512.0f) + FEPS);
  float s[8];
  *(float4*)&s[0] = *(const float4*)&scale[lane * 8];
  *(float4*)&s[4] = *(const float4*)&scale[lane * 8 + 4];
  float o[8];
#pragma unroll
  for (int u = 0; u < 8; u++) o[u] = x[u] * rsf * s[u];
  if (OMODE == 0 || OMODE == 2) {
    *(float4*)&outf[base] = *(float4*)&o[0];
    *(float4*)&outf[base + 4] = *(float4*)&o[4];
  }
  if (OMODE == 1 || OMODE == 2) {
    f16x8 h;
#pragma unroll
    for (int u = 0; u < 8; u++) h[u] = (half_t)o[u];
    *(f16x8*)&outh[base] = h;
  }
}

extern "C" void kernel_launch(void* const* d_in, const int* in_sizes, int n_in,
                              void* d_out, int out_size, void* d_ws, size_t ws_size,
                              hipStream_t stream) {
  (void)in_sizes; (void)n_in; (void)out_size; (void)ws_size;
  const float* x = (const float*)d_in[0];
  const float* obs = (const float*)d_in[1];
  const float* hs1 = (const float*)d_in[2];
  const float* hs2 = (const float*)d_in[3];
  const int* dones = (const int*)d_in[4];
  const int* tsid = (const int*)d_in[5];
  const float* ln1 = (const float*)d_in[6];
  const float* ln2 = (const float*)d_in[7];
  const float* ln3 = (const float*)d_in[8];
  const float* r1_gs = (const float*)d_in[14];
  const float* r1_gb = (const float*)d_in[15];
  const float* r2_gs = (const float*)d_in[21];
  const float* r2_gb = (const float*)d_in[22];

  const size_t NBUF = (size_t)NB * NS * NE;  // 2,097,152 elements
  char* ws = (char*)d_ws;
  int* segb = (int*)ws;                              // 16 KB
  float* fb = (float*)(ws + 16384);                  // 2 KB
  half_t* W16 = (half_t*)(ws + 18432);               // 13 x 512 KB
  char* p = ws + 18432 + (size_t)13 * NE * NE * sizeof(half_t);
  float* F0 = (float*)p;
  float* F1 = F0 + NBUF;
  float* F2 = F1 + NBUF;
  float* F3 = F2 + NBUF;
  float* F4 = F3 + NBUF;
  half_t* H0 = (half_t*)(F4 + NBUF);
  half_t* H1 = H0 + NBUF;
  half_t* H2 = H1 + NBUF;

  float* out = (float*)d_out;
  float* hs1o = out + NBUF;
  float* hs2o = hs1o + (size_t)NB * NH * ND * ND;

  // converted-weight slots: 0..4 = r1 wq,wk,wv,wg,wo; 5..9 = r2 wq,wk,wv,wg,wo;
  // 10..12 = ffn wg,wl,wo
  WCArgs wc;
  wc.src[0] = (const float*)d_in[9];   wc.src[1] = (const float*)d_in[10];
  wc.src[2] = (const float*)d_in[11];  wc.src[3] = (const float*)d_in[12];
  wc.src[4] = (const float*)d_in[13];  wc.src[5] = (const float*)d_in[16];
  wc.src[6] = (const float*)d_in[17];  wc.src[7] = (const float*)d_in[18];
  wc.src[8] = (const float*)d_in[19];  wc.src[9] = (const float*)d_in[20];
  wc.src[10] = (const float*)d_in[24]; wc.src[11] = (const float*)d_in[23];
  wc.src[12] = (const float*)d_in[25];
  wc.dst = W16;
  const half_t* WS[13];
  for (int i = 0; i < 13; i++) WS[i] = W16 + (size_t)i * NE * NE;

  dim3 gR(16, 32), gP2(8, 32);

  wconv_kernel<<<dim3(64, 13), 256, 0, stream>>>(wc);
  seg_scan_kernel<<<NB, 256, 0, stream>>>(dones, segb);
  conv_f2h_kernel<<<1024, 256, 0, stream>>>(x, H0);

  // ---- retention layer 1: q,k,v,g = x @ {wq,wk,wv,wg} ----
  {
    GArgs a = {H0, H0, H0, H0, WS[0], WS[1], WS[2], WS[3], F0, F1, F2, F3,
               1.0f, 0.125f, 1.0f, 1.0f};
    mfma_gemm_kernel<<<dim3(32, 32), 256, 0, stream>>>(a);
  }
  conv_f2h_kernel<<<1024, 256, 0, stream>>>(obs, H0);  // H0 free after G1
  ret_pass1_kernel<<<gR, 256, 0, stream>>>(F1, F2, segb, tsid, F4, fb);
  ret_pass2_kernel<<<gP2, 256, 0, stream>>>(F4, fb, hs1, F4, hs1o);
  ret_pass3_kernel<<<gR, 256, 0, stream>>>(F0, F1, F2, F4, F3, segb, tsid,
                                           r1_gs, r1_gb, H1);
  {  // o1 = (silu(g1)*gn1) @ wo
    GArgs a = {H1, H1, H1, H1, WS[4], WS[4], WS[4], WS[4], F0, F0, F0, F0,
               1.0f, 1.0f, 1.0f, 1.0f};
    mfma_gemm_kernel<<<dim3(8, 32), 256, 0, stream>>>(a);
  }
  rms_kernel<1><<<1024, 256, 0, stream>>>(F0, x, ln1, nullptr, H2);  // x2 -> H2

  // ---- retention layer 2: q2,g2 = obs@{wq,wg}; k2,v2 = x2@{wk,wv} ----
  {
    GArgs a = {H0, H0, H2, H2, WS[5], WS[8], WS[6], WS[7], F0, F3, F1, F2,
               1.0f, 1.0f, 0.125f, 1.0f};
    mfma_gemm_kernel<<<dim3(32, 32), 256, 0, stream>>>(a);
  }
  ret_pass1_kernel<<<gR, 256, 0, stream>>>(F1, F2, segb, tsid, F4, fb);
  ret_pass2_kernel<<<gP2, 256, 0, stream>>>(F4, fb, hs2, F4, hs2o);
  ret_pass3_kernel<<<gR, 256, 0, stream>>>(F0, F1, F2, F4, F3, segb, tsid,
                                           r2_gs, r2_gb, H1);
  {  // o2 = (silu(g2)*gn2) @ wo
    GArgs a = {H1, H1, H1, H1, WS[9], WS[9], WS[9], WS[9], F0, F0, F0, F0,
               1.0f, 1.0f, 1.0f, 1.0f};
    mfma_gemm_kernel<<<dim3(8, 32), 256, 0, stream>>>(a);
  }
  rms_kernel<2><<<1024, 256, 0, stream>>>(F0, obs, ln2, F1, H2);  // y -> F1 + H2

  // ---- FFN ----
  {
    GArgs a = {H2, H2, H2, H2, WS[10], WS[11], WS[10], WS[11], F0, F2, F0, F2,
               1.0f, 1.0f, 1.0f, 1.0f};
    mfma_gemm_kernel<<<dim3(16, 32), 256, 0, stream>>>(a);
  }
  silu_mul_conv_kernel<<<1024, 256, 0, stream>>>(F0, F2, H1);
  {
    GArgs a = {H1, H1, H1, H1, WS[12], WS[12], WS[12], WS[12], F3, F3, F3, F3,
               1.0f, 1.0f, 1.0f, 1.0f};
    mfma_gemm_kernel<<<dim3(8, 32), 256, 0, stream>>>(a);
  }
  rms_kernel<0><<<1024, 256, 0, stream>>>(F3, F1, ln3, out, nullptr);
}

// Round 6
// 297.859 us; speedup vs baseline: 3.7616x; 1.0715x over previous
//
#include <hip/hip_runtime.h>

#define NB 4
#define NS 1024
#define NE 512
#define NH 8
#define ND 64
#define NC 16      // chunks per sequence
#define CSZ 64     // chunk size

static constexpr float FEPS = 1e-6f;

typedef _Float16 half_t;
typedef __attribute__((ext_vector_type(8))) _Float16 f16x8;
typedef __attribute__((ext_vector_type(4))) float f32x4;

__device__ __forceinline__ float h_log2kap(int h) {
  float kap = (1.0f - exp2f(-5.0f - (float)h)) * 0.8f;
  return log2f(kap);
}
__device__ __forceinline__ float silu_f(float x) {
  return x / (1.0f + __expf(-x));
}

// ---------------- segment id scan (inclusive cumsum of dones) ----------------
__global__ __launch_bounds__(256) void seg_scan_kernel(const int* __restrict__ dones,
                                                       int* __restrict__ seg) {
  __shared__ int s[NS];
  int b = blockIdx.x;
  for (int i = threadIdx.x; i < NS; i += 256) s[i] = (dones[b * NS + i] != 0) ? 1 : 0;
  __syncthreads();
  for (int off = 1; off < NS; off <<= 1) {
    int tv[4];
#pragma unroll
    for (int u = 0; u < 4; u++) {
      int i = threadIdx.x + 256 * u;
      tv[u] = s[i] + ((i >= off) ? s[i - off] : 0);
    }
    __syncthreads();
#pragma unroll
    for (int u = 0; u < 4; u++) s[threadIdx.x + 256 * u] = tv[u];
    __syncthreads();
  }
  for (int i = threadIdx.x; i < NS; i += 256) seg[b * NS + i] = s[i];
}

// -------- weight convert+transpose: W[k][n] fp32 -> Wt[n][k] fp16, 13 mats ---
struct WCArgs {
  const float* src[13];
  half_t* dst;
};
__global__ __launch_bounds__(256) void wconv_kernel(WCArgs a) {
  __shared__ half_t T[64][72];  // [k][n] tile, padded
  const int t = threadIdx.x;
  const int w = blockIdx.y;
  const int kt = (blockIdx.x & 7) * 64;
  const int nt = (blockIdx.x >> 3) * 64;
  const float* src = a.src[w] + (size_t)kt * NE + nt;
  const int c = t & 63;
  for (int r = t >> 6; r < 64; r += 4) T[r][c] = (half_t)src[(size_t)r * NE + c];
  __syncthreads();
  const int n = t >> 2, kq = (t & 3) * 16;
  half_t* dst = a.dst + (size_t)w * NE * NE + (size_t)(nt + n) * NE + kt + kq;
  f16x8 o0, o1;
#pragma unroll
  for (int j = 0; j < 8; j++) {
    o0[j] = T[kq + j][n];
    o1[j] = T[kq + 8 + j][n];
  }
  *(f16x8*)dst = o0;
  *(f16x8*)(dst + 8) = o1;
}

// ---------------- fp16 MFMA GEMM: O[w] = f(A[w]) @ Wt[w]^T * alpha[w] --------
// Wt[w]: [n][k] fp16 (pre-transposed). Tile 128x64, BK=32, 4 waves.
// LDS swizzle: octet (r,o) at physical p=(o+(r>>1))&3 -> b128 reads 2-way free.
// amode: 0 = A fp16; 2 = A fp32 (convert in staging); 3 = silu(A)*A2 (both fp16)
// omode: 0 = fp32 out; 1 = fp16 out
struct GArgs {
  const void *A0, *A1, *A2i, *A3;
  const void *B0, *B1, *B2, *B3;   // second elementwise operand (amode 3)
  const half_t *W0, *W1, *W2, *W3;
  void *O0, *O1, *O2, *O3;
  float a0, a1, a2, a3;
  int am0, am1, am2, am3;
  int om0, om1, om2, om3;
};

__global__ __launch_bounds__(256, 4) void mfma_gemm_kernel(GArgs g) {
  __shared__ half_t As[128 * 32];
  __shared__ half_t Bs[64 * 32];
  const int t = threadIdx.x;
  const int bn = blockIdx.x;
  const int wsel = bn >> 3;
  const int n0 = (bn & 7) * 64;
  const int m0 = blockIdx.y * 128;
  const void* A = wsel == 0 ? g.A0 : wsel == 1 ? g.A1 : wsel == 2 ? g.A2i : g.A3;
  const void* A2 = wsel == 0 ? g.B0 : wsel == 1 ? g.B1 : wsel == 2 ? g.B2 : g.B3;
  const half_t* W = wsel == 0 ? g.W0 : wsel == 1 ? g.W1 : wsel == 2 ? g.W2 : g.W3;
  void* O = wsel == 0 ? g.O0 : wsel == 1 ? g.O1 : wsel == 2 ? g.O2 : g.O3;
  const float alpha = wsel == 0 ? g.a0 : wsel == 1 ? g.a1 : wsel == 2 ? g.a2 : g.a3;
  const int am = wsel == 0 ? g.am0 : wsel == 1 ? g.am1 : wsel == 2 ? g.am2 : g.am3;
  const int om = wsel == 0 ? g.om0 : wsel == 1 ? g.om1 : wsel == 2 ? g.om2 : g.om3;
  const int lane = t & 63;
  const int wv = t >> 6;
  const int ar = t >> 1;         // A staging: row 0..127
  const int ae = t & 1;          // A staging: 16-half chunk
  const int brn = t >> 2;        // B staging: n-row 0..63
  const int bo = t & 3;          // B staging: k-octet
  const int frow = lane & 15;
  const int fo = lane >> 4;      // fragment k-octet

  f32x4 acc[2][4];
#pragma unroll
  for (int i = 0; i < 2; i++)
#pragma unroll
    for (int j = 0; j < 4; j++) acc[i][j] = (f32x4){0.f, 0.f, 0.f, 0.f};

  const int ra0 = wv * 32 + frow;
  const int ra1 = ra0 + 16;
  const int offA0 = ra0 * 32 + (((fo + (ra0 >> 1)) & 3) * 8);
  const int offA1 = ra1 * 32 + (((fo + (ra1 >> 1)) & 3) * 8);
  int offB[4];
#pragma unroll
  for (int j = 0; j < 4; j++) {
    int rb = j * 16 + frow;
    offB[j] = rb * 32 + (((fo + (rb >> 1)) & 3) * 8);
  }
  const int p0 = ((2 * ae + 0) + (ar >> 1)) & 3;
  const int p1 = ((2 * ae + 1) + (ar >> 1)) & 3;
  const int pb = (bo + (brn >> 1)) & 3;

  for (int kt = 0; kt < NE; kt += 32) {
    const size_t gofs = (size_t)(m0 + ar) * NE + kt + ae * 16;
    f16x8 av0, av1;
    if (am == 0) {
      const half_t* ap = (const half_t*)A + gofs;
      av0 = *(const f16x8*)ap;
      av1 = *(const f16x8*)(ap + 8);
    } else if (am == 2) {
      const float* ap = (const float*)A + gofs;
      float4 f0 = *(const float4*)ap;
      float4 f1 = *(const float4*)(ap + 4);
      float4 f2 = *(const float4*)(ap + 8);
      float4 f3 = *(const float4*)(ap + 12);
      av0[0] = (half_t)f0.x; av0[1] = (half_t)f0.y; av0[2] = (half_t)f0.z; av0[3] = (half_t)f0.w;
      av0[4] = (half_t)f1.x; av0[5] = (half_t)f1.y; av0[6] = (half_t)f1.z; av0[7] = (half_t)f1.w;
      av1[0] = (half_t)f2.x; av1[1] = (half_t)f2.y; av1[2] = (half_t)f2.z; av1[3] = (half_t)f2.w;
      av1[4] = (half_t)f3.x; av1[5] = (half_t)f3.y; av1[6] = (half_t)f3.z; av1[7] = (half_t)f3.w;
    } else {  // am == 3: silu(a)*a2
      const half_t* ap = (const half_t*)A + gofs;
      const half_t* bp = (const half_t*)A2 + gofs;
      f16x8 a0 = *(const f16x8*)ap;
      f16x8 a1 = *(const f16x8*)(ap + 8);
      f16x8 b0 = *(const f16x8*)bp;
      f16x8 b1 = *(const f16x8*)(bp + 8);
#pragma unroll
      for (int e = 0; e < 8; e++) {
        av0[e] = (half_t)(silu_f((float)a0[e]) * (float)b0[e]);
        av1[e] = (half_t)(silu_f((float)a1[e]) * (float)b1[e]);
      }
    }
    const half_t* wp = W + (size_t)(n0 + brn) * NE + kt + bo * 8;
    f16x8 bv = *(const f16x8*)wp;
    *(f16x8*)&As[ar * 32 + p0 * 8] = av0;
    *(f16x8*)&As[ar * 32 + p1 * 8] = av1;
    *(f16x8*)&Bs[brn * 32 + pb * 8] = bv;
    __syncthreads();
    f16x8 af0 = *(const f16x8*)&As[offA0];
    f16x8 af1 = *(const f16x8*)&As[offA1];
#pragma unroll
    for (int j = 0; j < 4; j++) {
      f16x8 bf = *(const f16x8*)&Bs[offB[j]];
      acc[0][j] = __builtin_amdgcn_mfma_f32_16x16x32_f16(af0, bf, acc[0][j], 0, 0, 0);
      acc[1][j] = __builtin_amdgcn_mfma_f32_16x16x32_f16(af1, bf, acc[1][j], 0, 0, 0);
    }
    __syncthreads();
  }
  // epilogue: C/D layout col=lane&15, row=(lane>>4)*4+reg
#pragma unroll
  for (int i = 0; i < 2; i++) {
    int rb = m0 + wv * 32 + i * 16 + (lane >> 4) * 4;
#pragma unroll
    for (int j = 0; j < 4; j++) {
      int col = n0 + j * 16 + (lane & 15);
#pragma unroll
      for (int r = 0; r < 4; r++) {
        float val = acc[i][j][r] * alpha;
        if (om == 0) ((float*)O)[(size_t)(rb + r) * NE + col] = val;
        else ((half_t*)O)[(size_t)(rb + r) * NE + col] = (half_t)val;
      }
    }
  }
}

// ------- retention pass 1 (MFMA): U_c[d][v] = sum_j w_j k_j[d] v_j[v] --------
__global__ __launch_bounds__(256) void ret_pass1_kernel(
    const half_t* __restrict__ kmat, const half_t* __restrict__ vmat,
    const int* __restrict__ seg, const int* __restrict__ ts,
    float* __restrict__ U, float* __restrict__ fbuf) {
  __shared__ half_t KT[64 * 72];  // w-scaled K^T: [d][j]
  __shared__ half_t VT[64 * 72];  // V^T: [v][j]
  const int c = blockIdx.x, bh = blockIdx.y;
  const int b = bh >> 3, h = bh & 7;
  const float l2k = h_log2kap(h);
  const int t = threadIdx.x;
  const int r = t & 63, qd = t >> 6;  // staging: source row r=j, quarter qd
  const int e = c * CSZ + CSZ - 1;
  const int seg_e = seg[b * NS + e];
  const float ts_e = (float)ts[b * NS + e];
  {
    int gj = b * NS + c * CSZ + r;
    float w = (seg[gj] == seg_e) ? exp2f((ts_e - (float)ts[gj]) * l2k) : 0.0f;
    size_t gbase = (size_t)gj * NE + h * ND + qd * 16;
    f16x8 k0 = *(const f16x8*)&kmat[gbase];
    f16x8 k1 = *(const f16x8*)&kmat[gbase + 8];
    f16x8 v0 = *(const f16x8*)&vmat[gbase];
    f16x8 v1 = *(const f16x8*)&vmat[gbase + 8];
#pragma unroll
    for (int s = 0; s < 8; s++) {
      KT[(qd * 16 + s) * 72 + r] = (half_t)(w * (float)k0[s]);
      KT[(qd * 16 + 8 + s) * 72 + r] = (half_t)(w * (float)k1[s]);
      VT[(qd * 16 + s) * 72 + r] = v0[s];
      VT[(qd * 16 + 8 + s) * 72 + r] = v1[s];
    }
  }
  __syncthreads();
  const int lane = t & 63, wv = t >> 6;
  const int fr = lane & 15, fo8 = (lane >> 4) * 8;
  f32x4 acc[4];
#pragma unroll
  for (int j = 0; j < 4; j++) acc[j] = (f32x4){0.f, 0.f, 0.f, 0.f};
#pragma unroll
  for (int ks = 0; ks < 2; ks++) {
    f16x8 af = *(const f16x8*)&KT[(wv * 16 + fr) * 72 + ks * 32 + fo8];
#pragma unroll
    for (int nt = 0; nt < 4; nt++) {
      f16x8 bf = *(const f16x8*)&VT[(nt * 16 + fr) * 72 + ks * 32 + fo8];
      acc[nt] = __builtin_amdgcn_mfma_f32_16x16x32_f16(af, bf, acc[nt], 0, 0, 0);
    }
  }
  float* Uo = U + ((size_t)bh * NC + c) * (ND * ND);
  const int drow = wv * 16 + (lane >> 4) * 4;
#pragma unroll
  for (int nt = 0; nt < 4; nt++)
#pragma unroll
    for (int rg = 0; rg < 4; rg++)
      Uo[(drow + rg) * ND + nt * 16 + fr] = acc[nt][rg];
  if (t == 0) {
    int ps = 0;
    float pt = -1.0f;
    if (c > 0) {
      ps = seg[b * NS + c * CSZ - 1];
      pt = (float)ts[b * NS + c * CSZ - 1];
    }
    fbuf[bh * NC + c] = (seg_e == ps) ? exp2f((ts_e - pt) * l2k) : 0.0f;
  }
}

// -------- retention pass 2: scan over chunks (U/P alias: read-first) ---------
__global__ __launch_bounds__(256) void ret_pass2_kernel(
    const float* __restrict__ U, const float* __restrict__ fbuf,
    const float* __restrict__ hin, float* __restrict__ P,
    float* __restrict__ hout) {
  const int part = blockIdx.x;  // 0..7
  const int bh = blockIdx.y;    // 0..31
  const int idx = part * 512 + threadIdx.x * 2;
  float2 s = *(const float2*)&hin[bh * 4096 + idx];
  for (int c = 0; c < NC; c++) {
    float f = fbuf[bh * NC + c];
    float2 u = *(const float2*)&U[(bh * NC + c) * 4096 + idx];  // read BEFORE write
    *(float2*)&P[(bh * NC + c) * 4096 + idx] = s;
    s.x = u.x + f * s.x;
    s.y = u.y + f * s.y;
  }
  *(float2*)&hout[bh * 4096 + idx] = s;
}

// -------- retention pass 3 (MFMA): QK^T -> mask -> ScV + gQP -> gn -> gate ---
__global__ __launch_bounds__(256) void ret_pass3_kernel(
    const half_t* __restrict__ qmat, const half_t* __restrict__ kmat,
    const half_t* __restrict__ vmat, const float* __restrict__ P,
    const half_t* __restrict__ gmat,
    const int* __restrict__ seg, const int* __restrict__ ts,
    const float* __restrict__ gns, const float* __restrict__ gnb,
    half_t* __restrict__ y16) {
  __shared__ half_t Qs[64 * 72];  // Q natural [i][d]
  __shared__ half_t KS[64 * 72];  // K natural [j][d]; later Sc [i][j]
  __shared__ half_t VT[64 * 72];  // V^T [v][j]
  __shared__ half_t PT[64 * 72];  // P^T [v][d]
  __shared__ int segs[64];
  __shared__ int tss[64];
  __shared__ float gnsv[64];
  __shared__ float gnbv[64];
  const int c = blockIdx.x, bh = blockIdx.y;
  const int b = bh >> 3, h = bh & 7;
  const float l2k = h_log2kap(h);
  const int t = threadIdx.x;
  const int r = t & 63, qd = t >> 6;
  {
    size_t gbase = (size_t)(b * NS + c * CSZ + r) * NE + h * ND + qd * 16;
    f16x8 q0 = *(const f16x8*)&qmat[gbase];
    f16x8 q1 = *(const f16x8*)&qmat[gbase + 8];
    *(f16x8*)&Qs[r * 72 + qd * 16] = q0;
    *(f16x8*)&Qs[r * 72 + qd * 16 + 8] = q1;
    f16x8 k0 = *(const f16x8*)&kmat[gbase];
    f16x8 k1 = *(const f16x8*)&kmat[gbase + 8];
    *(f16x8*)&KS[r * 72 + qd * 16] = k0;
    *(f16x8*)&KS[r * 72 + qd * 16 + 8] = k1;
    f16x8 v0 = *(const f16x8*)&vmat[gbase];
    f16x8 v1 = *(const f16x8*)&vmat[gbase + 8];
    const float* pp = &P[((size_t)bh * NC + c) * 4096 + r * 64 + qd * 16];
#pragma unroll
    for (int s = 0; s < 8; s++) {
      VT[(qd * 16 + s) * 72 + r] = v0[s];
      VT[(qd * 16 + 8 + s) * 72 + r] = v1[s];
      PT[(qd * 16 + s) * 72 + r] = (half_t)pp[s];
      PT[(qd * 16 + 8 + s) * 72 + r] = (half_t)pp[8 + s];
    }
    if (t < 64) {
      segs[t] = seg[b * NS + c * CSZ + t];
      tss[t] = ts[b * NS + c * CSZ + t];
    } else if (t < 128) {
      gnsv[t - 64] = gns[h * ND + t - 64];
      gnbv[t - 64] = gnb[h * ND + t - 64];
    }
  }
  __syncthreads();
  const int lane = t & 63, wv = t >> 6;
  const int fr = lane & 15, fo8 = (lane >> 4) * 8;
  // ---- QK^T ----
  f32x4 aq[4];
#pragma unroll
  for (int j = 0; j < 4; j++) aq[j] = (f32x4){0.f, 0.f, 0.f, 0.f};
#pragma unroll
  for (int ks = 0; ks < 2; ks++) {
    f16x8 af = *(const f16x8*)&Qs[(wv * 16 + fr) * 72 + ks * 32 + fo8];
#pragma unroll
    for (int nt = 0; nt < 4; nt++) {
      f16x8 bf = *(const f16x8*)&KS[(nt * 16 + fr) * 72 + ks * 32 + fo8];
      aq[nt] = __builtin_amdgcn_mfma_f32_16x16x32_f16(af, bf, aq[nt], 0, 0, 0);
    }
  }
  __syncthreads();  // all K reads done -> KS becomes Sc
  // ---- decay/causal mask, write Sc[i][j] fp16 into KS ----
  const int qrow = wv * 16 + (lane >> 4) * 4;
#pragma unroll
  for (int nt = 0; nt < 4; nt++) {
    int j = nt * 16 + fr;
    int sj = segs[j];
    float tsj = (float)tss[j];
#pragma unroll
    for (int rg = 0; rg < 4; rg++) {
      int i = qrow + rg;
      float w = 0.0f;
      if (j <= i && sj == segs[i]) w = exp2f(((float)tss[i] - tsj) * l2k);
      KS[i * 72 + j] = (half_t)(aq[nt][rg] * w);
    }
  }
  __syncthreads();
  // ---- cross-decay factor g_i for this lane's A-row (i = wv*16 + fr) ----
  float gi;
  {
    int ps = 0;
    float pt = -1.0f;
    if (c > 0) {
      ps = seg[b * NS + c * CSZ - 1];
      pt = (float)ts[b * NS + c * CSZ - 1];
    }
    int i = wv * 16 + fr;
    gi = (segs[i] == ps) ? exp2f(((float)tss[i] - pt) * l2k) : 0.0f;
  }
  // ---- acc = Sc @ V + (g*Q) @ P ----
  f32x4 acc[4];
#pragma unroll
  for (int j = 0; j < 4; j++) acc[j] = (f32x4){0.f, 0.f, 0.f, 0.f};
#pragma unroll
  for (int ks = 0; ks < 2; ks++) {
    f16x8 saf = *(const f16x8*)&KS[(wv * 16 + fr) * 72 + ks * 32 + fo8];
    f16x8 qaf = *(const f16x8*)&Qs[(wv * 16 + fr) * 72 + ks * 32 + fo8];
    f16x8 gqf;
#pragma unroll
    for (int e = 0; e < 8; e++) gqf[e] = (half_t)(gi * (float)qaf[e]);
#pragma unroll
    for (int nt = 0; nt < 4; nt++) {
      f16x8 vbf = *(const f16x8*)&VT[(nt * 16 + fr) * 72 + ks * 32 + fo8];
      acc[nt] = __builtin_amdgcn_mfma_f32_16x16x32_f16(saf, vbf, acc[nt], 0, 0, 0);
      f16x8 pbf = *(const f16x8*)&PT[(nt * 16 + fr) * 72 + ks * 32 + fo8];
      acc[nt] = __builtin_amdgcn_mfma_f32_16x16x32_f16(gqf, pbf, acc[nt], 0, 0, 0);
    }
  }
  // ---- groupnorm over v (64) per row i, then silu(g)-gate, fp16 out ----
#pragma unroll
  for (int rg = 0; rg < 4; rg++) {
    float s1 = acc[0][rg] + acc[1][rg] + acc[2][rg] + acc[3][rg];
    float s2 = acc[0][rg] * acc[0][rg] + acc[1][rg] * acc[1][rg] +
               acc[2][rg] * acc[2][rg] + acc[3][rg] * acc[3][rg];
    s1 += __shfl_xor(s1, 1); s2 += __shfl_xor(s2, 1);
    s1 += __shfl_xor(s1, 2); s2 += __shfl_xor(s2, 2);
    s1 += __shfl_xor(s1, 4); s2 += __shfl_xor(s2, 4);
    s1 += __shfl_xor(s1, 8); s2 += __shfl_xor(s2, 8);
    float mu = s1 * (1.0f / 64.0f);
    float var = s2 * (1.0f / 64.0f) - mu * mu;
    float rs = rsqrtf(var + FEPS);
    int i = qrow + rg;
    size_t ybase = (size_t)(b * NS + c * CSZ + i) * NE + h * ND;
#pragma unroll
    for (int nt = 0; nt < 4; nt++) {
      int col = nt * 16 + fr;
      float gg = (float)gmat[ybase + col];
      float val = (acc[nt][rg] - mu) * rs * gnsv[col] + gnbv[col];
      y16[ybase + col] = (half_t)(silu_f(gg) * val);
    }
  }
}

// ------- residual RMS norm; OMODE 0: fp32 out, 1: fp16 out, 2: both ----------
template <int OMODE>
__global__ __launch_bounds__(256) void rms_kernel(const float* __restrict__ a,
                                                  const float* __restrict__ res,
                                                  const float* __restrict__ scale,
                                                  float* __restrict__ outf,
                                                  half_t* __restrict__ outh) {
  int row = blockIdx.x * 4 + (threadIdx.x >> 6);
  int lane = threadIdx.x & 63;
  int base = row * NE + lane * 8;
  float x[8], r[8];
  *(float4*)&x[0] = *(const float4*)&a[base];
  *(float4*)&x[4] = *(const float4*)&a[base + 4];
  *(float4*)&r[0] = *(const float4*)&res[base];
  *(float4*)&r[4] = *(const float4*)&res[base + 4];
  float ss = 0.f;
#pragma unroll
  for (int u = 0; u < 8; u++) {
    x[u] += r[u];
    ss += x[u] * x[u];
  }
#pragma unroll
  for (int off = 1; off < 64; off <<= 1) ss += __shfl_xor(ss, off);
  float rsf = rsqrtf(ss * (1.0f / 512.0f) + FEPS);
  float s[8];
  *(float4*)&s[0] = *(const float4*)&scale[lane * 8];
  *(float4*)&s[4] = *(const float4*)&scale[lane * 8 + 4];
  float o[8];
#pragma unroll
  for (int u = 0; u < 8; u++) o[u] = x[u] * rsf * s[u];
  if (OMODE == 0 || OMODE == 2) {
    *(float4*)&outf[base] = *(float4*)&o[0];
    *(float4*)&outf[base + 4] = *(float4*)&o[4];
  }
  if (OMODE == 1 || OMODE == 2) {
    f16x8 h;
#pragma unroll
    for (int u = 0; u < 8; u++) h[u] = (half_t)o[u];
    *(f16x8*)&outh[base] = h;
  }
}

extern "C" void kernel_launch(void* const* d_in, const int* in_sizes, int n_in,
                              void* d_out, int out_size, void* d_ws, size_t ws_size,
                              hipStream_t stream) {
  (void)in_sizes; (void)n_in; (void)out_size; (void)ws_size;
  const float* x = (const float*)d_in[0];
  const float* obs = (const float*)d_in[1];
  const float* hs1 = (const float*)d_in[2];
  const float* hs2 = (const float*)d_in[3];
  const int* dones = (const int*)d_in[4];
  const int* tsid = (const int*)d_in[5];
  const float* ln1 = (const float*)d_in[6];
  const float* ln2 = (const float*)d_in[7];
  const float* ln3 = (const float*)d_in[8];
  const float* r1_gs = (const float*)d_in[14];
  const float* r1_gb = (const float*)d_in[15];
  const float* r2_gs = (const float*)d_in[21];
  const float* r2_gb = (const float*)d_in[22];

  const size_t NBUF = (size_t)NB * NS * NE;  // 2,097,152 elements
  char* ws = (char*)d_ws;
  int* segb = (int*)ws;                              // 16 KB
  float* fb = (float*)(ws + 16384);                  // 2 KB
  half_t* W16 = (half_t*)(ws + 18432);               // 13 x 512 KB
  char* p = ws + 18432 + (size_t)13 * NE * NE * sizeof(half_t);
  float* F0 = (float*)p;                 // wo outputs (fp32)
  float* F1 = F0 + NBUF;                 // y (fp32)
  float* F3 = F1 + NBUF;                 // ffn out (fp32)
  float* FU = F3 + NBUF;                 // U / P (fp32, aliased in pass2)
  half_t* Hq = (half_t*)(FU + NBUF);
  half_t* Hk = Hq + NBUF;
  half_t* Hv = Hk + NBUF;
  half_t* Hg = Hv + NBUF;
  half_t* H1 = Hg + NBUF;                // pass3 output (gated, fp16)
  half_t* H2 = H1 + NBUF;                // rms fp16 output

  float* out = (float*)d_out;
  float* hs1o = out + NBUF;
  float* hs2o = hs1o + (size_t)NB * NH * ND * ND;

  // converted-weight slots: 0..4 = r1 wq,wk,wv,wg,wo; 5..9 = r2 wq,wk,wv,wg,wo;
  // 10..12 = ffn wg,wl,wo
  WCArgs wc;
  wc.src[0] = (const float*)d_in[9];   wc.src[1] = (const float*)d_in[10];
  wc.src[2] = (const float*)d_in[11];  wc.src[3] = (const float*)d_in[12];
  wc.src[4] = (const float*)d_in[13];  wc.src[5] = (const float*)d_in[16];
  wc.src[6] = (const float*)d_in[17];  wc.src[7] = (const float*)d_in[18];
  wc.src[8] = (const float*)d_in[19];  wc.src[9] = (const float*)d_in[20];
  wc.src[10] = (const float*)d_in[24]; wc.src[11] = (const float*)d_in[23];
  wc.src[12] = (const float*)d_in[25];
  wc.dst = W16;
  const half_t* WS[13];
  for (int i = 0; i < 13; i++) WS[i] = W16 + (size_t)i * NE * NE;

  dim3 gR(16, 32), gP2(8, 32);

  wconv_kernel<<<dim3(64, 13), 256, 0, stream>>>(wc);
  seg_scan_kernel<<<NB, 256, 0, stream>>>(dones, segb);

  // ---- retention layer 1: q,k,v,g = x @ {wq,wk,wv,wg} (cvt fused) ----
  {
    GArgs a = {x, x, x, x, nullptr, nullptr, nullptr, nullptr,
               WS[0], WS[1], WS[2], WS[3], Hq, Hk, Hv, Hg,
               1.0f, 0.125f, 1.0f, 1.0f, 2, 2, 2, 2, 1, 1, 1, 1};
    mfma_gemm_kernel<<<dim3(32, 32), 256, 0, stream>>>(a);
  }
  ret_pass1_kernel<<<gR, 256, 0, stream>>>(Hk, Hv, segb, tsid, FU, fb);
  ret_pass2_kernel<<<gP2, 256, 0, stream>>>(FU, fb, hs1, FU, hs1o);
  ret_pass3_kernel<<<gR, 256, 0, stream>>>(Hq, Hk, Hv, FU, Hg, segb, tsid,
                                           r1_gs, r1_gb, H1);
  {  // o1 = H1 @ wo -> F0 (fp32)
    GArgs a = {H1, H1, H1, H1, nullptr, nullptr, nullptr, nullptr,
               WS[4], WS[4], WS[4], WS[4], F0, F0, F0, F0,
               1.0f, 1.0f, 1.0f, 1.0f, 0, 0, 0, 0, 0, 0, 0, 0};
    mfma_gemm_kernel<<<dim3(8, 32), 256, 0, stream>>>(a);
  }
  rms_kernel<1><<<1024, 256, 0, stream>>>(F0, x, ln1, nullptr, H2);  // x2 -> H2

  // ---- retention layer 2: q2,g2 = obs@{wq,wg} (cvt); k2,v2 = x2@{wk,wv} ----
  {
    GArgs a = {obs, obs, H2, H2, nullptr, nullptr, nullptr, nullptr,
               WS[5], WS[8], WS[6], WS[7], Hq, Hg, Hk, Hv,
               1.0f, 1.0f, 0.125f, 1.0f, 2, 2, 0, 0, 1, 1, 1, 1};
    mfma_gemm_kernel<<<dim3(32, 32), 256, 0, stream>>>(a);
  }
  ret_pass1_kernel<<<gR, 256, 0, stream>>>(Hk, Hv, segb, tsid, FU, fb);
  ret_pass2_kernel<<<gP2, 256, 0, stream>>>(FU, fb, hs2, FU, hs2o);
  ret_pass3_kernel<<<gR, 256, 0, stream>>>(Hq, Hk, Hv, FU, Hg, segb, tsid,
                                           r2_gs, r2_gb, H1);
  {  // o2 = H1 @ wo -> F0
    GArgs a = {H1, H1, H1, H1, nullptr, nullptr, nullptr, nullptr,
               WS[9], WS[9], WS[9], WS[9], F0, F0, F0, F0,
               1.0f, 1.0f, 1.0f, 1.0f, 0, 0, 0, 0, 0, 0, 0, 0};
    mfma_gemm_kernel<<<dim3(8, 32), 256, 0, stream>>>(a);
  }
  rms_kernel<2><<<1024, 256, 0, stream>>>(F0, obs, ln2, F1, H2);  // y -> F1 + H2

  // ---- FFN: wg,wl from H2 -> Hq,Hk (fp16); fused silu in wo staging ----
  {
    GArgs a = {H2, H2, H2, H2, nullptr, nullptr, nullptr, nullptr,
               WS[10], WS[11], WS[10], WS[11], Hq, Hk, Hq, Hk,
               1.0f, 1.0f, 1.0f, 1.0f, 0, 0, 0, 0, 1, 1, 1, 1};
    mfma_gemm_kernel<<<dim3(16, 32), 256, 0, stream>>>(a);
  }
  {  // ffn = (silu(Hq) * Hk) @ wo -> F3
    GArgs a = {Hq, Hq, Hq, Hq, Hk, Hk, Hk, Hk,
               WS[12], WS[12], WS[12], WS[12], F3, F3, F3, F3,
               1.0f, 1.0f, 1.0f, 1.0f, 3, 3, 3, 3, 0, 0, 0, 0};
    mfma_gemm_kernel<<<dim3(8, 32), 256, 0, stream>>>(a);
  }
  rms_kernel<0><<<1024, 256, 0, stream>>>(F3, F1, ln3, out, nullptr);
}

// Round 7
// 297.567 us; speedup vs baseline: 3.7653x; 1.0010x over previous
//
#include <hip/hip_runtime.h>

#define NB 4
#define NS 1024
#define NE 512
#define NH 8
#define ND 64
#define NC 16      // chunks per sequence
#define CSZ 64     // chunk size

static constexpr float FEPS = 1e-6f;

typedef _Float16 half_t;
typedef __attribute__((ext_vector_type(8))) _Float16 f16x8;
typedef __attribute__((ext_vector_type(4))) float f32x4;

__device__ __forceinline__ float h_log2kap(int h) {
  float kap = (1.0f - exp2f(-5.0f - (float)h)) * 0.8f;
  return log2f(kap);
}
__device__ __forceinline__ float silu_f(float x) {
  return x / (1.0f + __expf(-x));
}

// ------ prep: weight convert+transpose (13 mats) + segment scan, one launch --
struct WCArgs {
  const float* src[13];
  half_t* dst;
  const int* dones;
  int* seg;
};
__global__ __launch_bounds__(256) void prep_kernel(WCArgs a) {
  __shared__ half_t T[64][72];  // [k][n] tile, padded
  __shared__ int s[NS];
  const int t = threadIdx.x;
  if (blockIdx.y < 13) {
    const int w = blockIdx.y;
    const int kt = (blockIdx.x & 7) * 64;
    const int nt = (blockIdx.x >> 3) * 64;
    const float* src = a.src[w] + (size_t)kt * NE + nt;
    const int c = t & 63;
    for (int r = t >> 6; r < 64; r += 4) T[r][c] = (half_t)src[(size_t)r * NE + c];
    __syncthreads();
    const int n = t >> 2, kq = (t & 3) * 16;
    half_t* dst = a.dst + (size_t)w * NE * NE + (size_t)(nt + n) * NE + kt + kq;
    f16x8 o0, o1;
#pragma unroll
    for (int j = 0; j < 8; j++) {
      o0[j] = T[kq + j][n];
      o1[j] = T[kq + 8 + j][n];
    }
    *(f16x8*)dst = o0;
    *(f16x8*)(dst + 8) = o1;
  } else {
    if (blockIdx.x >= NB) return;
    const int b = blockIdx.x;
    for (int i = t; i < NS; i += 256) s[i] = (a.dones[b * NS + i] != 0) ? 1 : 0;
    __syncthreads();
    for (int off = 1; off < NS; off <<= 1) {
      int tv[4];
#pragma unroll
      for (int u = 0; u < 4; u++) {
        int i = t + 256 * u;
        tv[u] = s[i] + ((i >= off) ? s[i - off] : 0);
      }
      __syncthreads();
#pragma unroll
      for (int u = 0; u < 4; u++) s[t + 256 * u] = tv[u];
      __syncthreads();
    }
    for (int i = t; i < NS; i += 256) a.seg[b * NS + i] = s[i];
  }
}

// ---------------- fp16 MFMA GEMM: O[w] = f(A[w]) @ Wt[w]^T * alpha[w] --------
// Wt[w]: [n][k] fp16 (pre-transposed). Tile 128 x (64*TN), BK=32, 4 waves.
// TN=2: waves 2x2, 4x4 frags (8 ds_read_b128 : 16 MFMA). TN=1: 4x1, 2x4 frags.
// LDS swizzle: octet (r,o) at physical p=(o+(r>>1))&3 -> b128 reads 2-way free.
// amode: 0 = A fp16; 2 = A fp32 (convert in staging); 3 = silu(A)*A2 (fp16)
// omode: 0 = fp32 out; 1 = fp16 out
struct GArgs {
  const void *A0, *A1, *A2i, *A3;
  const void *B0, *B1, *B2, *B3;   // second elementwise operand (amode 3)
  const half_t *W0, *W1, *W2, *W3;
  void *O0, *O1, *O2, *O3;
  float a0, a1, a2, a3;
  int am0, am1, am2, am3;
  int om0, om1, om2, om3;
};

template <int TN>
__global__ __launch_bounds__(256) void mfma_gemm_kernel(GArgs g) {
  constexpr int NT = 64 * TN;
  constexpr int NTILES = NE / NT;
  constexpr int MF = (TN == 2) ? 4 : 2;
  __shared__ half_t As[128 * 32];
  __shared__ half_t Bs[NT * 32];
  const int t = threadIdx.x;
  const int bn = blockIdx.x;
  const int wsel = bn / NTILES;
  const int n0 = (bn % NTILES) * NT;
  const int m0 = blockIdx.y * 128;
  const void* A = wsel == 0 ? g.A0 : wsel == 1 ? g.A1 : wsel == 2 ? g.A2i : g.A3;
  const void* A2 = wsel == 0 ? g.B0 : wsel == 1 ? g.B1 : wsel == 2 ? g.B2 : g.B3;
  const half_t* W = wsel == 0 ? g.W0 : wsel == 1 ? g.W1 : wsel == 2 ? g.W2 : g.W3;
  void* O = wsel == 0 ? g.O0 : wsel == 1 ? g.O1 : wsel == 2 ? g.O2 : g.O3;
  const float alpha = wsel == 0 ? g.a0 : wsel == 1 ? g.a1 : wsel == 2 ? g.a2 : g.a3;
  const int am = wsel == 0 ? g.am0 : wsel == 1 ? g.am1 : wsel == 2 ? g.am2 : g.am3;
  const int om = wsel == 0 ? g.om0 : wsel == 1 ? g.om1 : wsel == 2 ? g.om2 : g.om3;
  const int lane = t & 63;
  const int wv = t >> 6;
  const int ar = t >> 1;         // A staging: row 0..127
  const int ae = t & 1;          // A staging: 16-half chunk
  const int frow = lane & 15;
  const int fo = lane >> 4;      // fragment k-octet

  const int mbase = (TN == 2) ? (wv >> 1) * 64 : wv * 32;
  const int nbase = (TN == 2) ? (wv & 1) * 64 : 0;

  f32x4 acc[MF][4];
#pragma unroll
  for (int i = 0; i < MF; i++)
#pragma unroll
    for (int j = 0; j < 4; j++) acc[i][j] = (f32x4){0.f, 0.f, 0.f, 0.f};

  int offA[MF], offB[4];
#pragma unroll
  for (int fm = 0; fm < MF; fm++) {
    int r = mbase + fm * 16 + frow;
    offA[fm] = r * 32 + (((fo + (r >> 1)) & 3) * 8);
  }
#pragma unroll
  for (int fn = 0; fn < 4; fn++) {
    int r = nbase + fn * 16 + frow;
    offB[fn] = r * 32 + (((fo + (r >> 1)) & 3) * 8);
  }
  const int p0 = ((2 * ae + 0) + (ar >> 1)) & 3;
  const int p1 = ((2 * ae + 1) + (ar >> 1)) & 3;
  // B staging indices
  const int br2 = t >> 1, be2 = t & 1;              // TN==2 path (rows 0..127)
  const int br1 = t >> 2, bo1 = t & 3;              // TN==1 path (rows 0..63)
  const int pb1 = (bo1 + (br1 >> 1)) & 3;

  for (int kt = 0; kt < NE; kt += 32) {
    const size_t gofs = (size_t)(m0 + ar) * NE + kt + ae * 16;
    f16x8 av0, av1;
    if (am == 0) {
      const half_t* ap = (const half_t*)A + gofs;
      av0 = *(const f16x8*)ap;
      av1 = *(const f16x8*)(ap + 8);
    } else if (am == 2) {
      const float* ap = (const float*)A + gofs;
      float4 f0 = *(const float4*)ap;
      float4 f1 = *(const float4*)(ap + 4);
      float4 f2 = *(const float4*)(ap + 8);
      float4 f3 = *(const float4*)(ap + 12);
      av0[0] = (half_t)f0.x; av0[1] = (half_t)f0.y; av0[2] = (half_t)f0.z; av0[3] = (half_t)f0.w;
      av0[4] = (half_t)f1.x; av0[5] = (half_t)f1.y; av0[6] = (half_t)f1.z; av0[7] = (half_t)f1.w;
      av1[0] = (half_t)f2.x; av1[1] = (half_t)f2.y; av1[2] = (half_t)f2.z; av1[3] = (half_t)f2.w;
      av1[4] = (half_t)f3.x; av1[5] = (half_t)f3.y; av1[6] = (half_t)f3.z; av1[7] = (half_t)f3.w;
    } else {  // am == 3: silu(a)*a2
      const half_t* ap = (const half_t*)A + gofs;
      const half_t* bp = (const half_t*)A2 + gofs;
      f16x8 a0 = *(const f16x8*)ap;
      f16x8 a1 = *(const f16x8*)(ap + 8);
      f16x8 b0 = *(const f16x8*)bp;
      f16x8 b1 = *(const f16x8*)(bp + 8);
#pragma unroll
      for (int e = 0; e < 8; e++) {
        av0[e] = (half_t)(silu_f((float)a0[e]) * (float)b0[e]);
        av1[e] = (half_t)(silu_f((float)a1[e]) * (float)b1[e]);
      }
    }
    *(f16x8*)&As[ar * 32 + p0 * 8] = av0;
    *(f16x8*)&As[ar * 32 + p1 * 8] = av1;
    if (TN == 2) {
      const half_t* wp = W + (size_t)(n0 + br2) * NE + kt + be2 * 16;
      f16x8 bv0 = *(const f16x8*)wp;
      f16x8 bv1 = *(const f16x8*)(wp + 8);
      *(f16x8*)&Bs[br2 * 32 + p0 * 8] = bv0;
      *(f16x8*)&Bs[br2 * 32 + p1 * 8] = bv1;
    } else {
      const half_t* wp = W + (size_t)(n0 + br1) * NE + kt + bo1 * 8;
      f16x8 bv = *(const f16x8*)wp;
      *(f16x8*)&Bs[br1 * 32 + pb1 * 8] = bv;
    }
    __syncthreads();
    f16x8 af[MF], bf[4];
#pragma unroll
    for (int fm = 0; fm < MF; fm++) af[fm] = *(const f16x8*)&As[offA[fm]];
#pragma unroll
    for (int fn = 0; fn < 4; fn++) bf[fn] = *(const f16x8*)&Bs[offB[fn]];
#pragma unroll
    for (int fm = 0; fm < MF; fm++)
#pragma unroll
      for (int fn = 0; fn < 4; fn++)
        acc[fm][fn] = __builtin_amdgcn_mfma_f32_16x16x32_f16(af[fm], bf[fn], acc[fm][fn], 0, 0, 0);
    __syncthreads();
  }
  // epilogue: C/D layout col=lane&15, row=(lane>>4)*4+reg
#pragma unroll
  for (int fm = 0; fm < MF; fm++) {
    int rb = m0 + mbase + fm * 16 + (lane >> 4) * 4;
#pragma unroll
    for (int fn = 0; fn < 4; fn++) {
      int col = n0 + nbase + fn * 16 + frow;
#pragma unroll
      for (int r = 0; r < 4; r++) {
        float val = acc[fm][fn][r] * alpha;
        if (om == 0) ((float*)O)[(size_t)(rb + r) * NE + col] = val;
        else ((half_t*)O)[(size_t)(rb + r) * NE + col] = (half_t)val;
      }
    }
  }
}

// ------- retention pass 1 (MFMA): U_c[d][v] = sum_j w_j k_j[d] v_j[v] --------
__global__ __launch_bounds__(256) void ret_pass1_kernel(
    const half_t* __restrict__ kmat, const half_t* __restrict__ vmat,
    const int* __restrict__ seg, const int* __restrict__ ts,
    float* __restrict__ U, float* __restrict__ fbuf) {
  __shared__ half_t KT[64 * 72];  // w-scaled K^T: [d][j]
  __shared__ half_t VT[64 * 72];  // V^T: [v][j]
  const int c = blockIdx.x, bh = blockIdx.y;
  const int b = bh >> 3, h = bh & 7;
  const float l2k = h_log2kap(h);
  const int t = threadIdx.x;
  const int r = t & 63, qd = t >> 6;  // staging: source row r=j, quarter qd
  const int e = c * CSZ + CSZ - 1;
  const int seg_e = seg[b * NS + e];
  const float ts_e = (float)ts[b * NS + e];
  {
    int gj = b * NS + c * CSZ + r;
    float w = (seg[gj] == seg_e) ? exp2f((ts_e - (float)ts[gj]) * l2k) : 0.0f;
    size_t gbase = (size_t)gj * NE + h * ND + qd * 16;
    f16x8 k0 = *(const f16x8*)&kmat[gbase];
    f16x8 k1 = *(const f16x8*)&kmat[gbase + 8];
    f16x8 v0 = *(const f16x8*)&vmat[gbase];
    f16x8 v1 = *(const f16x8*)&vmat[gbase + 8];
#pragma unroll
    for (int s = 0; s < 8; s++) {
      KT[(qd * 16 + s) * 72 + r] = (half_t)(w * (float)k0[s]);
      KT[(qd * 16 + 8 + s) * 72 + r] = (half_t)(w * (float)k1[s]);
      VT[(qd * 16 + s) * 72 + r] = v0[s];
      VT[(qd * 16 + 8 + s) * 72 + r] = v1[s];
    }
  }
  __syncthreads();
  const int lane = t & 63, wv = t >> 6;
  const int fr = lane & 15, fo8 = (lane >> 4) * 8;
  f32x4 acc[4];
#pragma unroll
  for (int j = 0; j < 4; j++) acc[j] = (f32x4){0.f, 0.f, 0.f, 0.f};
#pragma unroll
  for (int ks = 0; ks < 2; ks++) {
    f16x8 af = *(const f16x8*)&KT[(wv * 16 + fr) * 72 + ks * 32 + fo8];
#pragma unroll
    for (int nt = 0; nt < 4; nt++) {
      f16x8 bf = *(const f16x8*)&VT[(nt * 16 + fr) * 72 + ks * 32 + fo8];
      acc[nt] = __builtin_amdgcn_mfma_f32_16x16x32_f16(af, bf, acc[nt], 0, 0, 0);
    }
  }
  float* Uo = U + ((size_t)bh * NC + c) * (ND * ND);
  const int drow = wv * 16 + (lane >> 4) * 4;
#pragma unroll
  for (int nt = 0; nt < 4; nt++)
#pragma unroll
    for (int rg = 0; rg < 4; rg++)
      Uo[(drow + rg) * ND + nt * 16 + fr] = acc[nt][rg];
  if (t == 0) {
    int ps = 0;
    float pt = -1.0f;
    if (c > 0) {
      ps = seg[b * NS + c * CSZ - 1];
      pt = (float)ts[b * NS + c * CSZ - 1];
    }
    fbuf[bh * NC + c] = (seg_e == ps) ? exp2f((ts_e - pt) * l2k) : 0.0f;
  }
}

// -------- retention pass 2: scan over chunks (U/P alias: read-first) ---------
__global__ __launch_bounds__(256) void ret_pass2_kernel(
    const float* __restrict__ U, const float* __restrict__ fbuf,
    const float* __restrict__ hin, float* __restrict__ P,
    float* __restrict__ hout) {
  const int part = blockIdx.x;  // 0..7
  const int bh = blockIdx.y;    // 0..31
  const int idx = part * 512 + threadIdx.x * 2;
  float2 s = *(const float2*)&hin[bh * 4096 + idx];
  for (int c = 0; c < NC; c++) {
    float f = fbuf[bh * NC + c];
    float2 u = *(const float2*)&U[(bh * NC + c) * 4096 + idx];  // read BEFORE write
    *(float2*)&P[(bh * NC + c) * 4096 + idx] = s;
    s.x = u.x + f * s.x;
    s.y = u.y + f * s.y;
  }
  *(float2*)&hout[bh * 4096 + idx] = s;
}

// -------- retention pass 3 (MFMA): QK^T -> mask -> ScV + gQP -> gn -> gate ---
__global__ __launch_bounds__(256) void ret_pass3_kernel(
    const half_t* __restrict__ qmat, const half_t* __restrict__ kmat,
    const half_t* __restrict__ vmat, const float* __restrict__ P,
    const half_t* __restrict__ gmat,
    const int* __restrict__ seg, const int* __restrict__ ts,
    const float* __restrict__ gns, const float* __restrict__ gnb,
    half_t* __restrict__ y16) {
  __shared__ half_t Qs[64 * 72];  // Q natural [i][d]
  __shared__ half_t KS[64 * 72];  // K natural [j][d]; later Sc [i][j]
  __shared__ half_t VT[64 * 72];  // V^T [v][j]
  __shared__ half_t PT[64 * 72];  // P^T [v][d]
  __shared__ int segs[64];
  __shared__ int tss[64];
  __shared__ float gnsv[64];
  __shared__ float gnbv[64];
  const int c = blockIdx.x, bh = blockIdx.y;
  const int b = bh >> 3, h = bh & 7;
  const float l2k = h_log2kap(h);
  const int t = threadIdx.x;
  const int r = t & 63, qd = t >> 6;
  {
    size_t gbase = (size_t)(b * NS + c * CSZ + r) * NE + h * ND + qd * 16;
    f16x8 q0 = *(const f16x8*)&qmat[gbase];
    f16x8 q1 = *(const f16x8*)&qmat[gbase + 8];
    *(f16x8*)&Qs[r * 72 + qd * 16] = q0;
    *(f16x8*)&Qs[r * 72 + qd * 16 + 8] = q1;
    f16x8 k0 = *(const f16x8*)&kmat[gbase];
    f16x8 k1 = *(const f16x8*)&kmat[gbase + 8];
    *(f16x8*)&KS[r * 72 + qd * 16] = k0;
    *(f16x8*)&KS[r * 72 + qd * 16 + 8] = k1;
    f16x8 v0 = *(const f16x8*)&vmat[gbase];
    f16x8 v1 = *(const f16x8*)&vmat[gbase + 8];
    const float* pp = &P[((size_t)bh * NC + c) * 4096 + r * 64 + qd * 16];
    float pv[16];
    *(float4*)&pv[0] = *(const float4*)pp;
    *(float4*)&pv[4] = *(const float4*)(pp + 4);
    *(float4*)&pv[8] = *(const float4*)(pp + 8);
    *(float4*)&pv[12] = *(const float4*)(pp + 12);
#pragma unroll
    for (int s = 0; s < 8; s++) {
      VT[(qd * 16 + s) * 72 + r] = v0[s];
      VT[(qd * 16 + 8 + s) * 72 + r] = v1[s];
      PT[(qd * 16 + s) * 72 + r] = (half_t)pv[s];
      PT[(qd * 16 + 8 + s) * 72 + r] = (half_t)pv[8 + s];
    }
    if (t < 64) {
      segs[t] = seg[b * NS + c * CSZ + t];
      tss[t] = ts[b * NS + c * CSZ + t];
    } else if (t < 128) {
      gnsv[t - 64] = gns[h * ND + t - 64];
      gnbv[t - 64] = gnb[h * ND + t - 64];
    }
  }
  __syncthreads();
  const int lane = t & 63, wv = t >> 6;
  const int fr = lane & 15, fo8 = (lane >> 4) * 8;
  // ---- QK^T ----
  f32x4 aq[4];
#pragma unroll
  for (int j = 0; j < 4; j++) aq[j] = (f32x4){0.f, 0.f, 0.f, 0.f};
#pragma unroll
  for (int ks = 0; ks < 2; ks++) {
    f16x8 af = *(const f16x8*)&Qs[(wv * 16 + fr) * 72 + ks * 32 + fo8];
#pragma unroll
    for (int nt = 0; nt < 4; nt++) {
      f16x8 bf = *(const f16x8*)&KS[(nt * 16 + fr) * 72 + ks * 32 + fo8];
      aq[nt] = __builtin_amdgcn_mfma_f32_16x16x32_f16(af, bf, aq[nt], 0, 0, 0);
    }
  }
  __syncthreads();  // all K reads done -> KS becomes Sc
  // ---- decay/causal mask, write Sc[i][j] fp16 into KS ----
  const int qrow = wv * 16 + (lane >> 4) * 4;
#pragma unroll
  for (int nt = 0; nt < 4; nt++) {
    int j = nt * 16 + fr;
    int sj = segs[j];
    float tsj = (float)tss[j];
#pragma unroll
    for (int rg = 0; rg < 4; rg++) {
      int i = qrow + rg;
      float w = 0.0f;
      if (j <= i && sj == segs[i]) w = exp2f(((float)tss[i] - tsj) * l2k);
      KS[i * 72 + j] = (half_t)(aq[nt][rg] * w);
    }
  }
  __syncthreads();
  // ---- cross-decay factor g_i for this lane's A-row (i = wv*16 + fr) ----
  float gi;
  {
    int ps = 0;
    float pt = -1.0f;
    if (c > 0) {
      ps = seg[b * NS + c * CSZ - 1];
      pt = (float)ts[b * NS + c * CSZ - 1];
    }
    int i = wv * 16 + fr;
    gi = (segs[i] == ps) ? exp2f(((float)tss[i] - pt) * l2k) : 0.0f;
  }
  // ---- acc = Sc @ V + (g*Q) @ P ----
  f32x4 acc[4];
#pragma unroll
  for (int j = 0; j < 4; j++) acc[j] = (f32x4){0.f, 0.f, 0.f, 0.f};
#pragma unroll
  for (int ks = 0; ks < 2; ks++) {
    f16x8 saf = *(const f16x8*)&KS[(wv * 16 + fr) * 72 + ks * 32 + fo8];
    f16x8 qaf = *(const f16x8*)&Qs[(wv * 16 + fr) * 72 + ks * 32 + fo8];
    f16x8 gqf;
#pragma unroll
    for (int e = 0; e < 8; e++) gqf[e] = (half_t)(gi * (float)qaf[e]);
#pragma unroll
    for (int nt = 0; nt < 4; nt++) {
      f16x8 vbf = *(const f16x8*)&VT[(nt * 16 + fr) * 72 + ks * 32 + fo8];
      acc[nt] = __builtin_amdgcn_mfma_f32_16x16x32_f16(saf, vbf, acc[nt], 0, 0, 0);
      f16x8 pbf = *(const f16x8*)&PT[(nt * 16 + fr) * 72 + ks * 32 + fo8];
      acc[nt] = __builtin_amdgcn_mfma_f32_16x16x32_f16(gqf, pbf, acc[nt], 0, 0, 0);
    }
  }
  // ---- groupnorm over v (64) per row i, then silu(g)-gate, fp16 out ----
#pragma unroll
  for (int rg = 0; rg < 4; rg++) {
    float s1 = acc[0][rg] + acc[1][rg] + acc[2][rg] + acc[3][rg];
    float s2 = acc[0][rg] * acc[0][rg] + acc[1][rg] * acc[1][rg] +
               acc[2][rg] * acc[2][rg] + acc[3][rg] * acc[3][rg];
    s1 += __shfl_xor(s1, 1); s2 += __shfl_xor(s2, 1);
    s1 += __shfl_xor(s1, 2); s2 += __shfl_xor(s2, 2);
    s1 += __shfl_xor(s1, 4); s2 += __shfl_xor(s2, 4);
    s1 += __shfl_xor(s1, 8); s2 += __shfl_xor(s2, 8);
    float mu = s1 * (1.0f / 64.0f);
    float var = s2 * (1.0f / 64.0f) - mu * mu;
    float rs = rsqrtf(var + FEPS);
    int i = qrow + rg;
    size_t ybase = (size_t)(b * NS + c * CSZ + i) * NE + h * ND;
#pragma unroll
    for (int nt = 0; nt < 4; nt++) {
      int col = nt * 16 + fr;
      float gg = (float)gmat[ybase + col];
      float val = (acc[nt][rg] - mu) * rs * gnsv[col] + gnbv[col];
      y16[ybase + col] = (half_t)(silu_f(gg) * val);
    }
  }
}

// ------- residual RMS norm; OMODE 0: fp32 out, 1: fp16 out, 2: both ----------
template <int OMODE>
__global__ __launch_bounds__(256) void rms_kernel(const float* __restrict__ a,
                                                  const float* __restrict__ res,
                                                  const float* __restrict__ scale,
                                                  float* __restrict__ outf,
                                                  half_t* __restrict__ outh) {
  int row = blockIdx.x * 4 + (threadIdx.x >> 6);
  int lane = threadIdx.x & 63;
  int base = row * NE + lane * 8;
  float x[8], r[8];
  *(float4*)&x[0] = *(const float4*)&a[base];
  *(float4*)&x[4] = *(const float4*)&a[base + 4];
  *(float4*)&r[0] = *(const float4*)&res[base];
  *(float4*)&r[4] = *(const float4*)&res[base + 4];
  float ss = 0.f;
#pragma unroll
  for (int u = 0; u < 8; u++) {
    x[u] += r[u];
    ss += x[u] * x[u];
  }
#pragma unroll
  for (int off = 1; off < 64; off <<= 1) ss += __shfl_xor(ss, off);
  float rsf = rsqrtf(ss * (1.0f / 512.0f) + FEPS);
  float s[8];
  *(float4*)&s[0] = *(const float4*)&scale[lane * 8];
  *(float4*)&s[4] = *(const float4*)&scale[lane * 8 + 4];
  float o[8];
#pragma unroll
  for (int u = 0; u < 8; u++) o[u] = x[u] * rsf * s[u];
  if (OMODE == 0 || OMODE == 2) {
    *(float4*)&outf[base] = *(float4*)&o[0];
    *(float4*)&outf[base + 4] = *(float4*)&o[4];
  }
  if (OMODE == 1 || OMODE == 2) {
    f16x8 h;
#pragma unroll
    for (int u = 0; u < 8; u++) h[u] = (half_t)o[u];
    *(f16x8*)&outh[base] = h;
  }
}

extern "C" void kernel_launch(void* const* d_in, const int* in_sizes, int n_in,
                              void* d_out, int out_size, void* d_ws, size_t ws_size,
                              hipStream_t stream) {
  (void)in_sizes; (void)n_in; (void)out_size; (void)ws_size;
  const float* x = (const float*)d_in[0];
  const float* obs = (const float*)d_in[1];
  const float* hs1 = (const float*)d_in[2];
  const float* hs2 = (const float*)d_in[3];
  const int* dones = (const int*)d_in[4];
  const int* tsid = (const int*)d_in[5];
  const float* ln1 = (const float*)d_in[6];
  const float* ln2 = (const float*)d_in[7];
  const float* ln3 = (const float*)d_in[8];
  const float* r1_gs = (const float*)d_in[14];
  const float* r1_gb = (const float*)d_in[15];
  const float* r2_gs = (const float*)d_in[21];
  const float* r2_gb = (const float*)d_in[22];

  const size_t NBUF = (size_t)NB * NS * NE;  // 2,097,152 elements
  char* ws = (char*)d_ws;
  int* segb = (int*)ws;                              // 16 KB
  float* fb = (float*)(ws + 16384);                  // 2 KB
  half_t* W16 = (half_t*)(ws + 18432);               // 13 x 512 KB
  char* p = ws + 18432 + (size_t)13 * NE * NE * sizeof(half_t);
  float* F0 = (float*)p;                 // wo outputs (fp32)
  float* F1 = F0 + NBUF;                 // y (fp32)
  float* F3 = F1 + NBUF;                 // ffn out (fp32)
  float* FU = F3 + NBUF;                 // U / P (fp32, aliased in pass2)
  half_t* Hq = (half_t*)(FU + NBUF);
  half_t* Hk = Hq + NBUF;
  half_t* Hv = Hk + NBUF;
  half_t* Hg = Hv + NBUF;
  half_t* H1 = Hg + NBUF;                // pass3 output (gated, fp16)
  half_t* H2 = H1 + NBUF;                // rms fp16 output

  float* out = (float*)d_out;
  float* hs1o = out + NBUF;
  float* hs2o = hs1o + (size_t)NB * NH * ND * ND;

  // converted-weight slots: 0..4 = r1 wq,wk,wv,wg,wo; 5..9 = r2 wq,wk,wv,wg,wo;
  // 10..12 = ffn wg,wl,wo
  WCArgs wc;
  wc.src[0] = (const float*)d_in[9];   wc.src[1] = (const float*)d_in[10];
  wc.src[2] = (const float*)d_in[11];  wc.src[3] = (const float*)d_in[12];
  wc.src[4] = (const float*)d_in[13];  wc.src[5] = (const float*)d_in[16];
  wc.src[6] = (const float*)d_in[17];  wc.src[7] = (const float*)d_in[18];
  wc.src[8] = (const float*)d_in[19];  wc.src[9] = (const float*)d_in[20];
  wc.src[10] = (const float*)d_in[24]; wc.src[11] = (const float*)d_in[23];
  wc.src[12] = (const float*)d_in[25];
  wc.dst = W16;
  wc.dones = dones;
  wc.seg = segb;
  const half_t* WS[13];
  for (int i = 0; i < 13; i++) WS[i] = W16 + (size_t)i * NE * NE;

  dim3 gR(16, 32), gP2(8, 32);

  prep_kernel<<<dim3(64, 14), 256, 0, stream>>>(wc);

  // ---- retention layer 1: q,k,v,g = x @ {wq,wk,wv,wg} (cvt fused) ----
  {
    GArgs a = {x, x, x, x, nullptr, nullptr, nullptr, nullptr,
               WS[0], WS[1], WS[2], WS[3], Hq, Hk, Hv, Hg,
               1.0f, 0.125f, 1.0f, 1.0f, 2, 2, 2, 2, 1, 1, 1, 1};
    mfma_gemm_kernel<2><<<dim3(16, 32), 256, 0, stream>>>(a);
  }
  ret_pass1_kernel<<<gR, 256, 0, stream>>>(Hk, Hv, segb, tsid, FU, fb);
  ret_pass2_kernel<<<gP2, 256, 0, stream>>>(FU, fb, hs1, FU, hs1o);
  ret_pass3_kernel<<<gR, 256, 0, stream>>>(Hq, Hk, Hv, FU, Hg, segb, tsid,
                                           r1_gs, r1_gb, H1);
  {  // o1 = H1 @ wo -> F0 (fp32)
    GArgs a = {H1, H1, H1, H1, nullptr, nullptr, nullptr, nullptr,
               WS[4], WS[4], WS[4], WS[4], F0, F0, F0, F0,
               1.0f, 1.0f, 1.0f, 1.0f, 0, 0, 0, 0, 0, 0, 0, 0};
    mfma_gemm_kernel<1><<<dim3(8, 32), 256, 0, stream>>>(a);
  }
  rms_kernel<1><<<1024, 256, 0, stream>>>(F0, x, ln1, nullptr, H2);  // x2 -> H2

  // ---- retention layer 2: q2,g2 = obs@{wq,wg} (cvt); k2,v2 = x2@{wk,wv} ----
  {
    GArgs a = {obs, obs, H2, H2, nullptr, nullptr, nullptr, nullptr,
               WS[5], WS[8], WS[6], WS[7], Hq, Hg, Hk, Hv,
               1.0f, 1.0f, 0.125f, 1.0f, 2, 2, 0, 0, 1, 1, 1, 1};
    mfma_gemm_kernel<2><<<dim3(16, 32), 256, 0, stream>>>(a);
  }
  ret_pass1_kernel<<<gR, 256, 0, stream>>>(Hk, Hv, segb, tsid, FU, fb);
  ret_pass2_kernel<<<gP2, 256, 0, stream>>>(FU, fb, hs2, FU, hs2o);
  ret_pass3_kernel<<<gR, 256, 0, stream>>>(Hq, Hk, Hv, FU, Hg, segb, tsid,
                                           r2_gs, r2_gb, H1);
  {  // o2 = H1 @ wo -> F0
    GArgs a = {H1, H1, H1, H1, nullptr, nullptr, nullptr, nullptr,
               WS[9], WS[9], WS[9], WS[9], F0, F0, F0, F0,
               1.0f, 1.0f, 1.0f, 1.0f, 0, 0, 0, 0, 0, 0, 0, 0};
    mfma_gemm_kernel<1><<<dim3(8, 32), 256, 0, stream>>>(a);
  }
  rms_kernel<2><<<1024, 256, 0, stream>>>(F0, obs, ln2, F1, H2);  // y -> F1 + H2

  // ---- FFN: wg,wl from H2 -> Hq,Hk (fp16); fused silu in wo staging ----
  {
    GArgs a = {H2, H2, H2, H2, nullptr, nullptr, nullptr, nullptr,
               WS[10], WS[11], WS[10], WS[11], Hq, Hk, Hq, Hk,
               1.0f, 1.0f, 1.0f, 1.0f, 0, 0, 0, 0, 1, 1, 1, 1};
    mfma_gemm_kernel<2><<<dim3(8, 32), 256, 0, stream>>>(a);
  }
  {  // ffn = (silu(Hq) * Hk) @ wo -> F3
    GArgs a = {Hq, Hq, Hq, Hq, Hk, Hk, Hk, Hk,
               WS[12], WS[12], WS[12], WS[12], F3, F3, F3, F3,
               1.0f, 1.0f, 1.0f, 1.0f, 3, 3, 3, 3, 0, 0, 0, 0};
    mfma_gemm_kernel<1><<<dim3(8, 32), 256, 0, stream>>>(a);
  }
  rms_kernel<0><<<1024, 256, 0, stream>>>(F3, F1, ln3, out, nullptr);
}